// Round 14
// baseline (179.011 us; speedup 1.0000x reference)
//
#include <hip/hip_runtime.h>

typedef unsigned short u16;
typedef unsigned int   u32;

#define BATCH  8192
#define DIM    100      // D
#define HID    110      // H
#define TSUB   19       // T = N-1 subnets
#define NSTEP  20       // N scan steps
#define KP     128      // padded K for MFMA
#define NPAD   112      // padded N (output cols) for tiles/storage
#define BN_EPS 1e-6f
#define DT_C   0.05f

#define SAB  2048                 // statsA blocks
#define SAR  (BATCH / SAB)        // 4 rows per block
#define SLICES 32                 // statsB slices
#define NBLK_SCAN 2048
#define NMT  64                   // gemm m-tiles

typedef __bf16 v8bf __attribute__((ext_vector_type(8)));
typedef float  v4f  __attribute__((ext_vector_type(4)));
typedef float  v2f  __attribute__((ext_vector_type(2)));
typedef u16    u16x4 __attribute__((ext_vector_type(4)));

__device__ __forceinline__ u16 f2bf(float f) {
    u32 u = __float_as_uint(f);
    return (u16)((u + 0x7fffu + ((u >> 16) & 1u)) >> 16);   // RNE
}
__device__ __forceinline__ float bf2f(u16 h) {
    return __uint_as_float(((u32)h) << 16);
}
__device__ __forceinline__ void acc4(float4& s, float4& q, float4 v) {
    s.x += v.x; s.y += v.y; s.z += v.z; s.w += v.w;
    q.x += v.x * v.x; q.y += v.y * v.y; q.z += v.z * v.z; q.w += v.w * v.w;
}

// ---------------------------------------------------------------------------
// statsA v2: explicit load-phase (12 independent float4 into named registers,
// launch_bounds(256,4) so the allocator CAN keep them in flight — VGPR=28 in
// v1 serialized them), then convert/accumulate/store. Tail loads clamped
// (tid>=13 duplicates lane 12's line: L1 hit, no divergence).
// ---------------------------------------------------------------------------
__global__ __launch_bounds__(256, 4)
void statsA(const float* __restrict__ x, float* __restrict__ part,
            u32* __restrict__ xT32) {
    __shared__ u16 xls[SAR][2112];
    const int tid = threadIdx.x;
    const int b0 = blockIdx.x * SAR;

    // ---- load phase: all rows' data issued before any use ----
    const float4* rp[SAR];
#pragma unroll
    for (int r = 0; r < SAR; r++)
        rp[r] = (const float4*)(x + (size_t)(b0 + r) * 2100);
    float4 va[SAR], vb[SAR], vc[SAR];
    const int tt = (tid < 13) ? tid : 12;
#pragma unroll
    for (int r = 0; r < SAR; r++) va[r] = rp[r][tid];
#pragma unroll
    for (int r = 0; r < SAR; r++) vb[r] = rp[r][tid + 256];
#pragma unroll
    for (int r = 0; r < SAR; r++) vc[r] = rp[r][tt + 512];

    // ---- use phase ----
    float4 s0 = {0,0,0,0}, q0 = {0,0,0,0};
    float4 s1 = {0,0,0,0}, q1 = {0,0,0,0};
    float4 s2 = {0,0,0,0}, q2 = {0,0,0,0};
#pragma unroll
    for (int r = 0; r < SAR; r++) {
        acc4(s0, q0, va[r]);
        acc4(s1, q1, vb[r]);
        u16x4 p0 = { f2bf(va[r].x), f2bf(va[r].y), f2bf(va[r].z), f2bf(va[r].w) };
        u16x4 p1 = { f2bf(vb[r].x), f2bf(vb[r].y), f2bf(vb[r].z), f2bf(vb[r].w) };
        *(u16x4*)&xls[r][tid * 4]        = p0;
        *(u16x4*)&xls[r][1024 + tid * 4] = p1;
        if (tid < 13) {
            acc4(s2, q2, vc[r]);
            u16x4 p2 = { f2bf(vc[r].x), f2bf(vc[r].y), f2bf(vc[r].z), f2bf(vc[r].w) };
            *(u16x4*)&xls[r][2048 + tid * 4] = p2;
        }
    }
    float* ps = part + (size_t)blockIdx.x * 4200;
    *(float4*)&ps[tid * 4]               = s0;
    *(float4*)&ps[1024 + tid * 4]        = s1;
    *(float4*)&ps[2100 + tid * 4]        = q0;
    *(float4*)&ps[2100 + 1024 + tid * 4] = q1;
    if (tid < 13) {
        *(float4*)&ps[2048 + tid * 4]        = s2;
        *(float4*)&ps[2100 + 2048 + tid * 4] = q2;
    }
    __syncthreads();
    const int TOT = TSUB * SAR * (NPAD / 2);   // 19*4*56
    for (int i = tid; i < TOT; i += 256) {
        int w = i % (NPAD / 2);
        int seg = i / (NPAD / 2);
        int r = seg % SAR, t = seg / SAR;
        int d0 = w * 2;
        u32 v = 0;
        if (d0 < DIM) {
            u16 lo = xls[r][d0 * 21 + t + 1];
            u16 hi = (d0 + 1 < DIM) ? xls[r][(d0 + 1) * 21 + t + 1] : (u16)0;
            v = (u32)lo | ((u32)hi << 16);
        }
        xT32[((size_t)t * BATCH + b0 + r) * (NPAD / 2) + w] = v;
    }
}

// statsB: slice partials -> slpart[slice][4200], PLAIN stores (no atomics)
__global__ void statsB(const float* __restrict__ part, float* __restrict__ slpart) {
    int gid = blockIdx.x * 256 + threadIdx.x;
    if (gid >= 4200 * SLICES) return;
    int slice = gid / 4200;
    int o = gid - slice * 4200;
    const float* p = part + (size_t)slice * (SAB / SLICES) * 4200 + o;
    float acc = 0.f;
#pragma unroll 8
    for (int i = 0; i < SAB / SLICES; i++) acc += p[(size_t)i * 4200];
    slpart[(size_t)slice * 4200 + o] = acc;
}

// ---------------------------------------------------------------------------
// wtrans: W[l][t][k][n] f32 -> WTsw[l][t][n][chunk-swizzled k] bf16.
// ---------------------------------------------------------------------------
__global__ void wtrans(const float* __restrict__ W0, const float* __restrict__ W1,
                       const float* __restrict__ W2, u16* __restrict__ WTsw) {
    __shared__ float lw[HID * HID];
    const int t = blockIdx.x, l = blockIdx.y, tid = threadIdx.x;
    const float* W; int K, N;
    if (l == 0)      { W = W0; K = DIM; N = HID; }
    else if (l == 1) { W = W1; K = HID; N = HID; }
    else             { W = W2; K = HID; N = DIM; }
    const float* Wt = W + (size_t)t * K * N;
    for (int i = tid; i < K * N; i += 256) lw[i] = Wt[i];
    __syncthreads();
    u16* out = WTsw + ((size_t)l * TSUB + t) * (NPAD * KP);
    for (int i = tid; i < NPAD * 16; i += 256) {
        int n = i / 16, p = i % 16;
        int kc = p ^ (n & 7);
        u16 o8[8];
#pragma unroll
        for (int j = 0; j < 8; j++) {
            int k = kc * 8 + j;
            float v = (k < K && n < N) ? lw[k * N + n] : 0.f;
            o8[j] = f2bf(v);
        }
        *(uint4*)&out[(size_t)n * KP + p * 8] = *(uint4*)o8;
    }
}

// ---------------------------------------------------------------------------
// GEMM v5: A direct global->registers; column stats via per-mt PLAIN-store
// partials gpart[mt][t][2][NPAD].
// AFFMODE 0: raw A.
// AFFMODE 1: affine from gpart partials (idx t*KREAL+k), c = b - m*ga.
// AFFMODE 2: scale-only from statsB slpart (idx k*21+(t+1), c = 0 — beta0
//            cancelled by next BN's shift invariance). Replaces scaleW0+statsC.
// ---------------------------------------------------------------------------
template <int KREAL, int NOUT, int AFFMODE, int RELU, int BMAJOR>
__global__ __launch_bounds__(512, 4)
void gemm_kernel(const u16* __restrict__ Ain,
                 const u16* __restrict__ WTswL,
                 const float* __restrict__ partIn,   // AFFMODE1: [64][T][2][NPAD]; AFFMODE2: slpart[32][4200]
                 const float* __restrict__ gIn,
                 const float* __restrict__ bIn,
                 u16* __restrict__ Hout,
                 float* __restrict__ partOut) {      // [64][T][2][NPAD]
    __shared__ __align__(16) u16 Blds[NPAD * KP];  // 28 KB
    __shared__ float s_sum[NPAD], s_sq[NPAD];
    __shared__ float aAffL[KP], cAffL[KP];

    const int tid = threadIdx.x;
    const int mt = blockIdx.x;
    const int t  = blockIdx.y;
    const int brow0 = mt * 128;

    if (tid < NPAD) { s_sum[tid] = 0.f; s_sq[tid] = 0.f; }
    if (AFFMODE) {
        if (tid >= KREAL && tid < KP) { aAffL[tid] = 0.f; cAffL[tid] = 0.f; }
        if (tid < KREAL) {
            float s = 0.f, q = 0.f;
            if (AFFMODE == 1) {
#pragma unroll 8
                for (int m2 = 0; m2 < NMT; m2++) {
                    const float* pp = partIn + ((size_t)(m2 * TSUB + t) * 2) * NPAD;
                    s += pp[tid];
                    q += pp[NPAD + tid];
                }
            } else {
                int idx = tid * 21 + (t + 1);
#pragma unroll 8
                for (int s2 = 0; s2 < SLICES; s2++) {
                    s += partIn[(size_t)s2 * 4200 + idx];
                    q += partIn[(size_t)s2 * 4200 + 2100 + idx];
                }
            }
            float m = s * (1.f / BATCH);
            float v = q * (1.f / BATCH) - m * m;
            float rstd = rsqrtf(v + BN_EPS);
            float ga = gIn[t * KREAL + tid] * rstd;
            aAffL[tid] = ga;
            cAffL[tid] = (AFFMODE == 2) ? 0.f : (bIn[t * KREAL + tid] - m * ga);
        }
    }

    // stage B (pre-swizzled plane, straight copy)
    {
        const uint4* wsrc = (const uint4*)(WTswL + (size_t)t * NPAD * KP);
        uint4* bl = (uint4*)Blds;
        for (int i = tid; i < NPAD * KP / 8; i += 512) bl[i] = wsrc[i];
    }
    __syncthreads();

    const int lane = tid & 63;
    const int wv   = tid >> 6;            // 0..7
    const int r0   = lane & 15;
    const int q    = lane >> 4;
    const int row  = wv * 16 + r0;        // 0..127

    // ---- A direct: 4 uint4 loads cover the lane's full K ----
    const u16* arow = Ain + ((size_t)t * BATCH + brow0 + row) * NPAD;
    u16 hv[4][8];
#pragma unroll
    for (int ks = 0; ks < 4; ks++) {
        int cb = ks * 4 + q;
        int cbl = (cb > 13) ? 13 : cb;    // clamp: k>=112 rows of B are zero
        *(uint4*)hv[ks] = *(const uint4*)(arow + cbl * 8);
    }
    v8bf afr[4];
#pragma unroll
    for (int ks = 0; ks < 4; ks++) {
        if (AFFMODE) {
            int cb = ks * 4 + q;          // k >= KREAL has a=c=0 -> frag 0
            const float* ap = &aAffL[cb * 8];
            const float* cp = &cAffL[cb * 8];
            u16 pk[8];
#pragma unroll
            for (int j = 0; j < 8; j++) {
                float av = fmaf(bf2f(hv[ks][j]), ap[j], cp[j]);
                if (RELU) av = fmaxf(av, 0.f);
                pk[j] = f2bf(av);
            }
            afr[ks] = *(v8bf*)pk;
        } else {
            afr[ks] = *(v8bf*)hv[ks];
        }
    }

    // ---- MFMA: wave owns 16 rows x 112 cols ----
    v4f acc[7];
#pragma unroll
    for (int j = 0; j < 7; j++) { v4f z = {0.f, 0.f, 0.f, 0.f}; acc[j] = z; }
#pragma unroll
    for (int ks = 0; ks < 4; ks++) {
        int cbase = ks * 4 + q;
#pragma unroll
        for (int nf = 0; nf < 7; nf++) {
            int nr = nf * 16 + r0;
            v8bf bfr = *(const v8bf*)&Blds[nr * KP + ((cbase ^ (nr & 7)) * 8)];
            acc[nf] = __builtin_amdgcn_mfma_f32_16x16x32_bf16(afr[ks], bfr, acc[nf], 0, 0, 0);
        }
    }

    // ---- epilogue: store bf16 pre-BN values + column stats ----
#pragma unroll
    for (int nf = 0; nf < 7; nf++) {
        int n = nf * 16 + r0;
#pragma unroll
        for (int rg = 0; rg < 4; rg++) {
            int grow = brow0 + wv * 16 + q * 4 + rg;
            size_t oidx = BMAJOR ? ((size_t)grow * (TSUB * NPAD) + (size_t)t * NPAD + n)
                                 : (((size_t)t * BATCH + grow) * NPAD + n);
            Hout[oidx] = f2bf(acc[nf][rg]);
        }
    }
#pragma unroll
    for (int nf = 0; nf < 7; nf++) {
        float cs = 0.f, cq = 0.f;
#pragma unroll
        for (int rg = 0; rg < 4; rg++) {
            float vv = acc[nf][rg];
            cs += vv; cq += vv * vv;
        }
        cs += __shfl_xor(cs, 16); cs += __shfl_xor(cs, 32);
        cq += __shfl_xor(cq, 16); cq += __shfl_xor(cq, 32);
        if (q == 0) {
            atomicAdd(&s_sum[nf * 16 + r0], cs);   // LDS-only combine across waves
            atomicAdd(&s_sq[nf * 16 + r0], cq);
        }
    }
    __syncthreads();
    if (tid < NPAD) {
        float* pp = partOut + ((size_t)(mt * TSUB + t) * 2) * NPAD;
        pp[tid]        = s_sum[tid];               // plain stores, no init needed
        pp[NPAD + tid] = s_sq[tid];
    }
}

// ---------------------------------------------------------------------------
// finalize3: BN affine for layer 3 from gemm2's gpart partials, packed per
// d-PAIR as {a0,c0,a1,c1} f32x4, 1/DIM folded.
// ---------------------------------------------------------------------------
__global__ void finalize3(const float* __restrict__ partIn,   // [64][T][2][NPAD]
                          const float* __restrict__ g3, const float* __restrict__ b3,
                          float4* __restrict__ acg) {
    int i = blockIdx.x * 256 + threadIdx.x;      // over 19*50 d-pairs
    if (i >= TSUB * 50) return;
    int t = i / 50, p = i - t * 50;
    float4 o;
#pragma unroll
    for (int h = 0; h < 2; h++) {
        int d = 2 * p + h;
        float s = 0.f, q = 0.f;
#pragma unroll 8
        for (int m2 = 0; m2 < NMT; m2++) {
            const float* pp = partIn + ((size_t)(m2 * TSUB + t) * 2) * NPAD;
            s += pp[d];
            q += pp[NPAD + d];
        }
        float m = s * (1.f / BATCH);
        float v = q * (1.f / BATCH) - m * m;
        float rstd = rsqrtf(v + BN_EPS);
        int e = t * DIM + d;
        float ga = g3[e] * rstd * (1.f / DIM);
        float cc = b3[e] * (1.f / DIM) - m * ga;
        if (h == 0) { o.x = ga; o.y = cc; } else { o.z = ga; o.w = cc; }
    }
    acg[i] = o;
}

// ---------------------------------------------------------------------------
// Scan (R7/R9 structure; launch_bounds(256,4) -> VGPR cap 128, no asm spills).
// ---------------------------------------------------------------------------
__global__ __launch_bounds__(256, 4)
void scan_kernel(const float* __restrict__ dw,
                 const u16* __restrict__ zbuf,          // [B][T][NPAD] (b-major)
                 const float4* __restrict__ acg,        // [19][50] {a0,c0,a1,c1}
                 const float* __restrict__ z_init, const float* __restrict__ y_init,
                 float* __restrict__ yout, float* __restrict__ mred) {
    __shared__ float bsum[NSTEP];
    const int tid = threadIdx.x;
    if (tid < NSTEP) bsum[tid] = 0.f;
    __syncthreads();

    const int wv = tid >> 6, lane = tid & 63;
    const int b = blockIdx.x * 4 + wv;
    const int ll = (lane < 50) ? lane : 49;            // clamp for loads

    v4f w[10];
    u32 zr[TSUB];
    v2f zi;
    {
        const float* dwaddr = dw + (size_t)b * (DIM * NSTEP) + ll * 40;
        const u16*   zaddr  = zbuf + (size_t)b * (TSUB * NPAD) + 2 * ll;
        const float* ziaddr = z_init + 2 * ll;
        asm volatile("global_load_dwordx4 %0, %1, off offset:0"   : "=v"(w[0]) : "v"(dwaddr));
        asm volatile("global_load_dwordx4 %0, %1, off offset:16"  : "=v"(w[1]) : "v"(dwaddr));
        asm volatile("global_load_dwordx4 %0, %1, off offset:32"  : "=v"(w[2]) : "v"(dwaddr));
        asm volatile("global_load_dwordx4 %0, %1, off offset:48"  : "=v"(w[3]) : "v"(dwaddr));
        asm volatile("global_load_dwordx4 %0, %1, off offset:64"  : "=v"(w[4]) : "v"(dwaddr));
        asm volatile("global_load_dwordx4 %0, %1, off offset:80"  : "=v"(w[5]) : "v"(dwaddr));
        asm volatile("global_load_dwordx4 %0, %1, off offset:96"  : "=v"(w[6]) : "v"(dwaddr));
        asm volatile("global_load_dwordx4 %0, %1, off offset:112" : "=v"(w[7]) : "v"(dwaddr));
        asm volatile("global_load_dwordx4 %0, %1, off offset:128" : "=v"(w[8]) : "v"(dwaddr));
        asm volatile("global_load_dwordx4 %0, %1, off offset:144" : "=v"(w[9]) : "v"(dwaddr));
#pragma unroll
        for (int t = 0; t < TSUB; t++)
            asm volatile("global_load_dword %0, %1, off offset:%2"
                         : "=v"(zr[t]) : "v"(zaddr), "i"(t * NPAD * 2));
        asm volatile("global_load_dwordx2 %0, %1, off" : "=v"(zi) : "v"(ziaddr));
        asm volatile("s_waitcnt vmcnt(0)" ::: "memory");
        __builtin_amdgcn_sched_barrier(0);
    }

    float acc[NSTEP];
#pragma unroll
    for (int k = 0; k < NSTEP; k++) acc[k] = 0.f;
    if (lane < 50) {
        acc[0] = zi[0] * w[0][0] + zi[1] * w[5][0];
#pragma unroll
        for (int t = 0; t < TSUB; t++) {
            float4 ac = acg[t * 50 + ll];
            u32 z = zr[t];
            float za0 = fmaf(bf2f((u16)(z & 0xffffu)), ac.x, ac.y);
            float za1 = fmaf(bf2f((u16)(z >> 16)),     ac.z, ac.w);
            const int n = t + 1, j = n >> 2, k = n & 3;   // compile-time per unrolled t
            acc[n] += w[j][k] * za0 + w[5 + j][k] * za1;
        }
    }

#pragma unroll
    for (int m = 1; m < 64; m <<= 1) {
#pragma unroll
        for (int k = 0; k < NSTEP; k++) acc[k] += __shfl_xor(acc[k], m, 64);
    }

    const float yi = y_init[0];
    float y = yi, ysave = 0.f;
#pragma unroll
    for (int i = 0; i < NSTEP; i++) {
        y = y - DT_C * __sinf(y) + acc[i];
        if (i == lane - 1) ysave = y;                  // lane n holds y_n
    }
    if (lane == 0) yout[b] = y;                        // y_final = y_20
    if (lane >= 1 && lane < NSTEP) atomicAdd(&bsum[lane], ysave);
    __syncthreads();
    if (tid >= 1 && tid < NSTEP) mred[blockIdx.x * NSTEP + tid] = bsum[tid];
}

// ---------------------------------------------------------------------------
// meanred: meanout[n] = mean over batch of y_n (block n sums 2048 partials).
// ---------------------------------------------------------------------------
__global__ void meanred(const float* __restrict__ mred, const float* __restrict__ y_init,
                        float* __restrict__ meanout) {
    const int n = blockIdx.x, tid = threadIdx.x;
    if (n == 0) { if (tid == 0) meanout[0] = y_init[0]; return; }
    float s = 0.f;
    for (int i = tid; i < NBLK_SCAN; i += 256) s += mred[(size_t)i * NSTEP + n];
#pragma unroll
    for (int m = 1; m < 64; m <<= 1) s += __shfl_xor(s, m, 64);
    __shared__ float ws4[4];
    if ((tid & 63) == 0) ws4[tid >> 6] = s;
    __syncthreads();
    if (tid == 0) meanout[n] = (ws4[0] + ws4[1] + ws4[2] + ws4[3]) * (1.f / BATCH);
}

// ---------------------------------------------------------------------------
extern "C" void kernel_launch(void* const* d_in, const int* in_sizes, int n_in,
                              void* d_out, int out_size, void* d_ws, size_t ws_size,
                              hipStream_t stream) {
    const float* dw     = (const float*)d_in[0];
    const float* x      = (const float*)d_in[1];
    const float* y_init = (const float*)d_in[3];
    const float* z_init = (const float*)d_in[4];
    const float* g0 = (const float*)d_in[5];
    const float* W0 = (const float*)d_in[7];
    const float* g1 = (const float*)d_in[8];
    const float* b1 = (const float*)d_in[9];
    const float* W1 = (const float*)d_in[10];
    const float* g2 = (const float*)d_in[11];
    const float* b2 = (const float*)d_in[12];
    const float* W2 = (const float*)d_in[13];
    // d_in[6]=beta0 (cancelled via shift-invariance), d_in[14]=bias2 (cancelled)
    const float* g3 = (const float*)d_in[15];
    const float* b3 = (const float*)d_in[16];

    char* ws = (char*)d_ws;
    size_t off = 0;
    auto alloc = [&](size_t bytes) -> void* {
        off = (off + 255) & ~(size_t)255;
        void* p = ws + off;
        off += bytes;
        return p;
    };

    float* slpart = (float*)alloc((size_t)SLICES * 4200 * 4);         // 537 KB
    float* gp0    = (float*)alloc((size_t)NMT * TSUB * 2 * NPAD * 4); // 1.09 MB
    float* gp1    = (float*)alloc((size_t)NMT * TSUB * 2 * NPAD * 4); // 1.09 MB

    u16* WTsw = (u16*)alloc((size_t)3 * TSUB * NPAD * KP * 2);
    float4* acg = (float4*)alloc((size_t)TSUB * 50 * 16);             // 15.2 KB
    float* mred = (float*)alloc((size_t)NBLK_SCAN * NSTEP * 4);       // 160 KB

    const size_t hBytes = (size_t)TSUB * BATCH * NPAD * 2;            // 34.9 MB
    u16* h0 = (u16*)alloc(hBytes);
    u16* h1 = (u16*)alloc(hBytes);
    u16* outbuf = h0;                 // b-major [B][T][NPAD]; h0 dead after gemm1
    float* part = (float*)h0;         // statsA partials alias h0 (34.4 MB <= 34.9)
    u32*  xT32  = (u32*)h1;           // xT aliases h1

    float* yout = (float*)d_out;
    float* meanout = yout + BATCH;

    // 9 dispatches, no memsets: all stats paths deterministically written.
    wtrans<<<dim3(TSUB, 3), 256, 0, stream>>>(W0, W1, W2, WTsw);
    statsA<<<SAB, 256, 0, stream>>>(x, part, xT32);
    statsB<<<(4200 * SLICES + 255) / 256, 256, 0, stream>>>(part, slpart);

    const u16* xT = (const u16*)xT32;
    u16* WT0 = WTsw;
    u16* WT1 = WTsw + (size_t)TSUB * NPAD * KP;
    u16* WT2 = WTsw + (size_t)2 * TSUB * NPAD * KP;

    gemm_kernel<DIM, HID, 2, 0, 0><<<dim3(NMT, TSUB), 512, 0, stream>>>(xT, WT0, slpart, g0, nullptr, h0, gp0);
    gemm_kernel<HID, HID, 1, 1, 0><<<dim3(NMT, TSUB), 512, 0, stream>>>(h0, WT1, gp0, g1, b1, h1, gp1);
    gemm_kernel<HID, DIM, 1, 1, 1><<<dim3(NMT, TSUB), 512, 0, stream>>>(h1, WT2, gp1, g2, b2, outbuf, gp0);

    finalize3<<<4, 256, 0, stream>>>(gp0, g3, b3, acg);
    scan_kernel<<<NBLK_SCAN, 256, 0, stream>>>(dw, outbuf, acg, z_init, y_init, yout, mred);
    meanred<<<NSTEP, 256, 0, stream>>>(mred, y_init, meanout);
}

// Round 15
// 174.302 us; speedup vs baseline: 1.0270x; 1.0270x over previous
//
#include <hip/hip_runtime.h>

typedef unsigned short u16;
typedef unsigned int   u32;

#define BATCH  8192
#define DIM    100      // D
#define HID    110      // H
#define TSUB   19       // T = N-1 subnets
#define NSTEP  20       // N scan steps
#define KP     128      // padded K for MFMA
#define NPAD   112      // padded N (output cols) for tiles/storage
#define BN_EPS 1e-6f
#define DT_C   0.05f

#define SAB  2048                 // statsA blocks
#define SAR  (BATCH / SAB)        // 4 rows per block
#define SLICES 32                 // statsB slices
#define NBLK_SCAN 2048
#define NMT  64                   // gemm m-tiles

typedef __bf16 v8bf __attribute__((ext_vector_type(8)));
typedef float  v4f  __attribute__((ext_vector_type(4)));
typedef float  v2f  __attribute__((ext_vector_type(2)));
typedef u16    u16x4 __attribute__((ext_vector_type(4)));

__device__ __forceinline__ u16 f2bf(float f) {
    u32 u = __float_as_uint(f);
    return (u16)((u + 0x7fffu + ((u >> 16) & 1u)) >> 16);   // RNE
}
__device__ __forceinline__ float bf2f(u16 h) {
    return __uint_as_float(((u32)h) << 16);
}
__device__ __forceinline__ void acc4(float4& s, float4& q, float4 v) {
    s.x += v.x; s.y += v.y; s.z += v.z; s.w += v.w;
    q.x += v.x * v.x; q.y += v.y * v.y; q.z += v.z * v.z; q.w += v.w * v.w;
}

// ---------------------------------------------------------------------------
// statsA v2 (kept from R14: left the top-5): explicit load-phase with
// launch_bounds(256,4) so all 12 float4 stay in flight.
// ---------------------------------------------------------------------------
__global__ __launch_bounds__(256, 4)
void statsA(const float* __restrict__ x, float* __restrict__ part,
            u32* __restrict__ xT32) {
    __shared__ u16 xls[SAR][2112];
    const int tid = threadIdx.x;
    const int b0 = blockIdx.x * SAR;

    const float4* rp[SAR];
#pragma unroll
    for (int r = 0; r < SAR; r++)
        rp[r] = (const float4*)(x + (size_t)(b0 + r) * 2100);
    float4 va[SAR], vb[SAR], vc[SAR];
    const int tt = (tid < 13) ? tid : 12;
#pragma unroll
    for (int r = 0; r < SAR; r++) va[r] = rp[r][tid];
#pragma unroll
    for (int r = 0; r < SAR; r++) vb[r] = rp[r][tid + 256];
#pragma unroll
    for (int r = 0; r < SAR; r++) vc[r] = rp[r][tt + 512];

    float4 s0 = {0,0,0,0}, q0 = {0,0,0,0};
    float4 s1 = {0,0,0,0}, q1 = {0,0,0,0};
    float4 s2 = {0,0,0,0}, q2 = {0,0,0,0};
#pragma unroll
    for (int r = 0; r < SAR; r++) {
        acc4(s0, q0, va[r]);
        acc4(s1, q1, vb[r]);
        u16x4 p0 = { f2bf(va[r].x), f2bf(va[r].y), f2bf(va[r].z), f2bf(va[r].w) };
        u16x4 p1 = { f2bf(vb[r].x), f2bf(vb[r].y), f2bf(vb[r].z), f2bf(vb[r].w) };
        *(u16x4*)&xls[r][tid * 4]        = p0;
        *(u16x4*)&xls[r][1024 + tid * 4] = p1;
        if (tid < 13) {
            acc4(s2, q2, vc[r]);
            u16x4 p2 = { f2bf(vc[r].x), f2bf(vc[r].y), f2bf(vc[r].z), f2bf(vc[r].w) };
            *(u16x4*)&xls[r][2048 + tid * 4] = p2;
        }
    }
    float* ps = part + (size_t)blockIdx.x * 4200;
    *(float4*)&ps[tid * 4]               = s0;
    *(float4*)&ps[1024 + tid * 4]        = s1;
    *(float4*)&ps[2100 + tid * 4]        = q0;
    *(float4*)&ps[2100 + 1024 + tid * 4] = q1;
    if (tid < 13) {
        *(float4*)&ps[2048 + tid * 4]        = s2;
        *(float4*)&ps[2100 + 2048 + tid * 4] = q2;
    }
    __syncthreads();
    const int TOT = TSUB * SAR * (NPAD / 2);   // 19*4*56
    for (int i = tid; i < TOT; i += 256) {
        int w = i % (NPAD / 2);
        int seg = i / (NPAD / 2);
        int r = seg % SAR, t = seg / SAR;
        int d0 = w * 2;
        u32 v = 0;
        if (d0 < DIM) {
            u16 lo = xls[r][d0 * 21 + t + 1];
            u16 hi = (d0 + 1 < DIM) ? xls[r][(d0 + 1) * 21 + t + 1] : (u16)0;
            v = (u32)lo | ((u32)hi << 16);
        }
        xT32[((size_t)t * BATCH + b0 + r) * (NPAD / 2) + w] = v;
    }
}

// statsB: slice partials -> slpart[slice][4200], plain stores
__global__ void statsB(const float* __restrict__ part, float* __restrict__ slpart) {
    int gid = blockIdx.x * 256 + threadIdx.x;
    if (gid >= 4200 * SLICES) return;
    int slice = gid / 4200;
    int o = gid - slice * 4200;
    const float* p = part + (size_t)slice * (SAB / SLICES) * 4200 + o;
    float acc = 0.f;
#pragma unroll 8
    for (int i = 0; i < SAB / SLICES; i++) acc += p[(size_t)i * 4200];
    slpart[(size_t)slice * 4200 + o] = acc;
}

// ---------------------------------------------------------------------------
// wtrans: W[l][t][k][n] f32 -> WTsw[l][t][n][chunk-swizzled k] bf16.
// ---------------------------------------------------------------------------
__global__ void wtrans(const float* __restrict__ W0, const float* __restrict__ W1,
                       const float* __restrict__ W2, u16* __restrict__ WTsw) {
    __shared__ float lw[HID * HID];
    const int t = blockIdx.x, l = blockIdx.y, tid = threadIdx.x;
    const float* W; int K, N;
    if (l == 0)      { W = W0; K = DIM; N = HID; }
    else if (l == 1) { W = W1; K = HID; N = HID; }
    else             { W = W2; K = HID; N = DIM; }
    const float* Wt = W + (size_t)t * K * N;
    for (int i = tid; i < K * N; i += 256) lw[i] = Wt[i];
    __syncthreads();
    u16* out = WTsw + ((size_t)l * TSUB + t) * (NPAD * KP);
    for (int i = tid; i < NPAD * 16; i += 256) {
        int n = i / 16, p = i % 16;
        int kc = p ^ (n & 7);
        u16 o8[8];
#pragma unroll
        for (int j = 0; j < 8; j++) {
            int k = kc * 8 + j;
            float v = (k < K && n < N) ? lw[k * N + n] : 0.f;
            o8[j] = f2bf(v);
        }
        *(uint4*)&out[(size_t)n * KP + p * 8] = *(uint4*)o8;
    }
}

// ---------------------------------------------------------------------------
// finalize0: layer-0 scale table aff0[T][2][KP] from statsB slices.
// a = gamma0*rstd, c = 0 (beta0 cancelled by next BN's shift invariance).
// ---------------------------------------------------------------------------
__global__ void finalize0(const float* __restrict__ slpart, const float* __restrict__ g0,
                          float* __restrict__ aff0) {
    const int t = blockIdx.x, tid = threadIdx.x;   // 128 threads
    float a = 0.f;
    if (tid < DIM) {
        int idx = tid * 21 + (t + 1);
        float s = 0.f, q = 0.f;
#pragma unroll 8
        for (int s2 = 0; s2 < SLICES; s2++) {
            s += slpart[(size_t)s2 * 4200 + idx];
            q += slpart[(size_t)s2 * 4200 + 2100 + idx];
        }
        float m = s * (1.f / BATCH);
        float v = q * (1.f / BATCH) - m * m;
        a = g0[t * DIM + tid] * rsqrtf(v + BN_EPS);
    }
    aff0[(size_t)t * 2 * KP + tid]      = a;
    aff0[(size_t)t * 2 * KP + KP + tid] = 0.f;
}

// ---------------------------------------------------------------------------
// finalizeAff: reduce gpart [NMT][T][2][NPAD] -> aff[T][2][KP] (a, c).
// COALESCED: thread tid reads element tid of each contiguous 112-float panel.
// k >= KREAL zeroed. This removes the serialized scatter from the GEMMs.
// ---------------------------------------------------------------------------
template <int KREAL>
__global__ void finalizeAff(const float* __restrict__ partIn,
                            const float* __restrict__ g, const float* __restrict__ b,
                            float* __restrict__ aff) {
    const int t = blockIdx.x, tid = threadIdx.x;   // 128 threads
    float a = 0.f, c = 0.f;
    if (tid < KREAL) {
        float s = 0.f, q = 0.f;
#pragma unroll 8
        for (int m2 = 0; m2 < NMT; m2++) {
            const float* pp = partIn + ((size_t)(m2 * TSUB + t) * 2) * NPAD;
            s += pp[tid];
            q += pp[NPAD + tid];
        }
        float m = s * (1.f / BATCH);
        float v = q * (1.f / BATCH) - m * m;
        float rstd = rsqrtf(v + BN_EPS);
        float ga = g[t * KREAL + tid] * rstd;
        a = ga;
        c = b[t * KREAL + tid] - m * ga;
    }
    aff[(size_t)t * 2 * KP + tid]      = a;
    aff[(size_t)t * 2 * KP + KP + tid] = c;
}

// ---------------------------------------------------------------------------
// GEMM v6: A direct global->registers; BN affine read COALESCED from the
// precomputed aff[T][2][KP] table (2 loads, no in-kernel reduction scatter).
// Column stats out via per-mt plain-store partials gpart[mt][t][2][NPAD].
// ---------------------------------------------------------------------------
template <int RELU, int BMAJOR>
__global__ __launch_bounds__(512, 4)
void gemm_kernel(const u16* __restrict__ Ain,
                 const u16* __restrict__ WTswL,
                 const float* __restrict__ aff,      // [T][2][KP]
                 u16* __restrict__ Hout,
                 float* __restrict__ partOut) {      // [64][T][2][NPAD]
    __shared__ __align__(16) u16 Blds[NPAD * KP];  // 28 KB
    __shared__ float s_sum[NPAD], s_sq[NPAD];
    __shared__ float aAffL[KP], cAffL[KP];

    const int tid = threadIdx.x;
    const int mt = blockIdx.x;
    const int t  = blockIdx.y;
    const int brow0 = mt * 128;

    if (tid < NPAD) { s_sum[tid] = 0.f; s_sq[tid] = 0.f; }
    if (tid < KP) {
        aAffL[tid] = aff[(size_t)t * 2 * KP + tid];
        cAffL[tid] = aff[(size_t)t * 2 * KP + KP + tid];
    }

    // stage B (pre-swizzled plane, straight copy)
    {
        const uint4* wsrc = (const uint4*)(WTswL + (size_t)t * NPAD * KP);
        uint4* bl = (uint4*)Blds;
        for (int i = tid; i < NPAD * KP / 8; i += 512) bl[i] = wsrc[i];
    }
    __syncthreads();

    const int lane = tid & 63;
    const int wv   = tid >> 6;            // 0..7
    const int r0   = lane & 15;
    const int q    = lane >> 4;
    const int row  = wv * 16 + r0;        // 0..127

    // ---- A direct: 4 uint4 loads cover the lane's full K ----
    const u16* arow = Ain + ((size_t)t * BATCH + brow0 + row) * NPAD;
    u16 hv[4][8];
#pragma unroll
    for (int ks = 0; ks < 4; ks++) {
        int cb = ks * 4 + q;
        int cbl = (cb > 13) ? 13 : cb;    // clamp: k>=112 rows of B are zero
        *(uint4*)hv[ks] = *(const uint4*)(arow + cbl * 8);
    }
    v8bf afr[4];
#pragma unroll
    for (int ks = 0; ks < 4; ks++) {
        int cb = ks * 4 + q;              // k >= KREAL has a=c=0 -> frag 0
        const float* ap = &aAffL[cb * 8];
        const float* cp = &cAffL[cb * 8];
        u16 pk[8];
#pragma unroll
        for (int j = 0; j < 8; j++) {
            float av = fmaf(bf2f(hv[ks][j]), ap[j], cp[j]);
            if (RELU) av = fmaxf(av, 0.f);
            pk[j] = f2bf(av);
        }
        afr[ks] = *(v8bf*)pk;
    }

    // ---- MFMA: wave owns 16 rows x 112 cols ----
    v4f acc[7];
#pragma unroll
    for (int j = 0; j < 7; j++) { v4f z = {0.f, 0.f, 0.f, 0.f}; acc[j] = z; }
#pragma unroll
    for (int ks = 0; ks < 4; ks++) {
        int cbase = ks * 4 + q;
#pragma unroll
        for (int nf = 0; nf < 7; nf++) {
            int nr = nf * 16 + r0;
            v8bf bfr = *(const v8bf*)&Blds[nr * KP + ((cbase ^ (nr & 7)) * 8)];
            acc[nf] = __builtin_amdgcn_mfma_f32_16x16x32_bf16(afr[ks], bfr, acc[nf], 0, 0, 0);
        }
    }

    // ---- epilogue: store bf16 pre-BN values + column stats ----
#pragma unroll
    for (int nf = 0; nf < 7; nf++) {
        int n = nf * 16 + r0;
#pragma unroll
        for (int rg = 0; rg < 4; rg++) {
            int grow = brow0 + wv * 16 + q * 4 + rg;
            size_t oidx = BMAJOR ? ((size_t)grow * (TSUB * NPAD) + (size_t)t * NPAD + n)
                                 : (((size_t)t * BATCH + grow) * NPAD + n);
            Hout[oidx] = f2bf(acc[nf][rg]);
        }
    }
#pragma unroll
    for (int nf = 0; nf < 7; nf++) {
        float cs = 0.f, cq = 0.f;
#pragma unroll
        for (int rg = 0; rg < 4; rg++) {
            float vv = acc[nf][rg];
            cs += vv; cq += vv * vv;
        }
        cs += __shfl_xor(cs, 16); cs += __shfl_xor(cs, 32);
        cq += __shfl_xor(cq, 16); cq += __shfl_xor(cq, 32);
        if (q == 0) {
            atomicAdd(&s_sum[nf * 16 + r0], cs);   // LDS-only combine across waves
            atomicAdd(&s_sq[nf * 16 + r0], cq);
        }
    }
    __syncthreads();
    if (tid < NPAD) {
        float* pp = partOut + ((size_t)(mt * TSUB + t) * 2) * NPAD;
        pp[tid]        = s_sum[tid];
        pp[NPAD + tid] = s_sq[tid];
    }
}

// ---------------------------------------------------------------------------
// finalize3: BN affine for layer 3 from gemm2's gpart partials, packed per
// d-PAIR as {a0,c0,a1,c1} f32x4, 1/DIM folded. Coalesced per-thread reads
// are not possible here (pair layout), but 4 blocks of work: negligible.
// ---------------------------------------------------------------------------
__global__ void finalize3(const float* __restrict__ partIn,   // [64][T][2][NPAD]
                          const float* __restrict__ g3, const float* __restrict__ b3,
                          float4* __restrict__ acg) {
    int i = blockIdx.x * 256 + threadIdx.x;      // over 19*50 d-pairs
    if (i >= TSUB * 50) return;
    int t = i / 50, p = i - t * 50;
    float4 o;
#pragma unroll
    for (int h = 0; h < 2; h++) {
        int d = 2 * p + h;
        float s = 0.f, q = 0.f;
#pragma unroll 8
        for (int m2 = 0; m2 < NMT; m2++) {
            const float* pp = partIn + ((size_t)(m2 * TSUB + t) * 2) * NPAD;
            s += pp[d];
            q += pp[NPAD + d];
        }
        float m = s * (1.f / BATCH);
        float v = q * (1.f / BATCH) - m * m;
        float rstd = rsqrtf(v + BN_EPS);
        int e = t * DIM + d;
        float ga = g3[e] * rstd * (1.f / DIM);
        float cc = b3[e] * (1.f / DIM) - m * ga;
        if (h == 0) { o.x = ga; o.y = cc; } else { o.z = ga; o.w = cc; }
    }
    acg[i] = o;
}

// ---------------------------------------------------------------------------
// Scan (R7/R9 structure; launch_bounds(256,4) -> VGPR cap 128, no asm spills).
// ---------------------------------------------------------------------------
__global__ __launch_bounds__(256, 4)
void scan_kernel(const float* __restrict__ dw,
                 const u16* __restrict__ zbuf,          // [B][T][NPAD] (b-major)
                 const float4* __restrict__ acg,        // [19][50] {a0,c0,a1,c1}
                 const float* __restrict__ z_init, const float* __restrict__ y_init,
                 float* __restrict__ yout, float* __restrict__ mred) {
    __shared__ float bsum[NSTEP];
    const int tid = threadIdx.x;
    if (tid < NSTEP) bsum[tid] = 0.f;
    __syncthreads();

    const int wv = tid >> 6, lane = tid & 63;
    const int b = blockIdx.x * 4 + wv;
    const int ll = (lane < 50) ? lane : 49;            // clamp for loads

    v4f w[10];
    u32 zr[TSUB];
    v2f zi;
    {
        const float* dwaddr = dw + (size_t)b * (DIM * NSTEP) + ll * 40;
        const u16*   zaddr  = zbuf + (size_t)b * (TSUB * NPAD) + 2 * ll;
        const float* ziaddr = z_init + 2 * ll;
        asm volatile("global_load_dwordx4 %0, %1, off offset:0"   : "=v"(w[0]) : "v"(dwaddr));
        asm volatile("global_load_dwordx4 %0, %1, off offset:16"  : "=v"(w[1]) : "v"(dwaddr));
        asm volatile("global_load_dwordx4 %0, %1, off offset:32"  : "=v"(w[2]) : "v"(dwaddr));
        asm volatile("global_load_dwordx4 %0, %1, off offset:48"  : "=v"(w[3]) : "v"(dwaddr));
        asm volatile("global_load_dwordx4 %0, %1, off offset:64"  : "=v"(w[4]) : "v"(dwaddr));
        asm volatile("global_load_dwordx4 %0, %1, off offset:80"  : "=v"(w[5]) : "v"(dwaddr));
        asm volatile("global_load_dwordx4 %0, %1, off offset:96"  : "=v"(w[6]) : "v"(dwaddr));
        asm volatile("global_load_dwordx4 %0, %1, off offset:112" : "=v"(w[7]) : "v"(dwaddr));
        asm volatile("global_load_dwordx4 %0, %1, off offset:128" : "=v"(w[8]) : "v"(dwaddr));
        asm volatile("global_load_dwordx4 %0, %1, off offset:144" : "=v"(w[9]) : "v"(dwaddr));
#pragma unroll
        for (int t = 0; t < TSUB; t++)
            asm volatile("global_load_dword %0, %1, off offset:%2"
                         : "=v"(zr[t]) : "v"(zaddr), "i"(t * NPAD * 2));
        asm volatile("global_load_dwordx2 %0, %1, off" : "=v"(zi) : "v"(ziaddr));
        asm volatile("s_waitcnt vmcnt(0)" ::: "memory");
        __builtin_amdgcn_sched_barrier(0);
    }

    float acc[NSTEP];
#pragma unroll
    for (int k = 0; k < NSTEP; k++) acc[k] = 0.f;
    if (lane < 50) {
        acc[0] = zi[0] * w[0][0] + zi[1] * w[5][0];
#pragma unroll
        for (int t = 0; t < TSUB; t++) {
            float4 ac = acg[t * 50 + ll];
            u32 z = zr[t];
            float za0 = fmaf(bf2f((u16)(z & 0xffffu)), ac.x, ac.y);
            float za1 = fmaf(bf2f((u16)(z >> 16)),     ac.z, ac.w);
            const int n = t + 1, j = n >> 2, k = n & 3;   // compile-time per unrolled t
            acc[n] += w[j][k] * za0 + w[5 + j][k] * za1;
        }
    }

#pragma unroll
    for (int m = 1; m < 64; m <<= 1) {
#pragma unroll
        for (int k = 0; k < NSTEP; k++) acc[k] += __shfl_xor(acc[k], m, 64);
    }

    const float yi = y_init[0];
    float y = yi, ysave = 0.f;
#pragma unroll
    for (int i = 0; i < NSTEP; i++) {
        y = y - DT_C * __sinf(y) + acc[i];
        if (i == lane - 1) ysave = y;                  // lane n holds y_n
    }
    if (lane == 0) yout[b] = y;                        // y_final = y_20
    if (lane >= 1 && lane < NSTEP) atomicAdd(&bsum[lane], ysave);
    __syncthreads();
    if (tid >= 1 && tid < NSTEP) mred[blockIdx.x * NSTEP + tid] = bsum[tid];
}

// ---------------------------------------------------------------------------
// meanred: meanout[n] = mean over batch of y_n (block n sums 2048 partials).
// ---------------------------------------------------------------------------
__global__ void meanred(const float* __restrict__ mred, const float* __restrict__ y_init,
                        float* __restrict__ meanout) {
    const int n = blockIdx.x, tid = threadIdx.x;
    if (n == 0) { if (tid == 0) meanout[0] = y_init[0]; return; }
    float s = 0.f;
    for (int i = tid; i < NBLK_SCAN; i += 256) s += mred[(size_t)i * NSTEP + n];
#pragma unroll
    for (int m = 1; m < 64; m <<= 1) s += __shfl_xor(s, m, 64);
    __shared__ float ws4[4];
    if ((tid & 63) == 0) ws4[tid >> 6] = s;
    __syncthreads();
    if (tid == 0) meanout[n] = (ws4[0] + ws4[1] + ws4[2] + ws4[3]) * (1.f / BATCH);
}

// ---------------------------------------------------------------------------
extern "C" void kernel_launch(void* const* d_in, const int* in_sizes, int n_in,
                              void* d_out, int out_size, void* d_ws, size_t ws_size,
                              hipStream_t stream) {
    const float* dw     = (const float*)d_in[0];
    const float* x      = (const float*)d_in[1];
    const float* y_init = (const float*)d_in[3];
    const float* z_init = (const float*)d_in[4];
    const float* g0 = (const float*)d_in[5];
    const float* W0 = (const float*)d_in[7];
    const float* g1 = (const float*)d_in[8];
    const float* b1 = (const float*)d_in[9];
    const float* W1 = (const float*)d_in[10];
    const float* g2 = (const float*)d_in[11];
    const float* b2 = (const float*)d_in[12];
    const float* W2 = (const float*)d_in[13];
    // d_in[6]=beta0 (cancelled via shift-invariance), d_in[14]=bias2 (cancelled)
    const float* g3 = (const float*)d_in[15];
    const float* b3 = (const float*)d_in[16];

    char* ws = (char*)d_ws;
    size_t off = 0;
    auto alloc = [&](size_t bytes) -> void* {
        off = (off + 255) & ~(size_t)255;
        void* p = ws + off;
        off += bytes;
        return p;
    };

    float* slpart = (float*)alloc((size_t)SLICES * 4200 * 4);         // 537 KB
    float* gp0    = (float*)alloc((size_t)NMT * TSUB * 2 * NPAD * 4); // 1.09 MB
    float* gp1    = (float*)alloc((size_t)NMT * TSUB * 2 * NPAD * 4); // 1.09 MB
    float* aff0   = (float*)alloc((size_t)TSUB * 2 * KP * 4);         // 19.5 KB
    float* aff1   = (float*)alloc((size_t)TSUB * 2 * KP * 4);
    float* aff2   = (float*)alloc((size_t)TSUB * 2 * KP * 4);

    u16* WTsw = (u16*)alloc((size_t)3 * TSUB * NPAD * KP * 2);
    float4* acg = (float4*)alloc((size_t)TSUB * 50 * 16);             // 15.2 KB
    float* mred = (float*)alloc((size_t)NBLK_SCAN * NSTEP * 4);       // 160 KB

    const size_t hBytes = (size_t)TSUB * BATCH * NPAD * 2;            // 34.9 MB
    u16* h0 = (u16*)alloc(hBytes);
    u16* h1 = (u16*)alloc(hBytes);
    u16* outbuf = h0;                 // b-major [B][T][NPAD]; h0 dead after gemm1
    float* part = (float*)h0;         // statsA partials alias h0 (34.4 MB <= 34.9)
    u32*  xT32  = (u32*)h1;           // xT aliases h1

    float* yout = (float*)d_out;
    float* meanout = yout + BATCH;

    wtrans<<<dim3(TSUB, 3), 256, 0, stream>>>(W0, W1, W2, WTsw);
    statsA<<<SAB, 256, 0, stream>>>(x, part, xT32);
    statsB<<<(4200 * SLICES + 255) / 256, 256, 0, stream>>>(part, slpart);
    finalize0<<<TSUB, 128, 0, stream>>>(slpart, g0, aff0);

    const u16* xT = (const u16*)xT32;
    u16* WT0 = WTsw;
    u16* WT1 = WTsw + (size_t)TSUB * NPAD * KP;
    u16* WT2 = WTsw + (size_t)2 * TSUB * NPAD * KP;

    gemm_kernel<0, 0><<<dim3(NMT, TSUB), 512, 0, stream>>>(xT, WT0, aff0, h0, gp0);
    finalizeAff<HID><<<TSUB, 128, 0, stream>>>(gp0, g1, b1, aff1);
    gemm_kernel<1, 0><<<dim3(NMT, TSUB), 512, 0, stream>>>(h0, WT1, aff1, h1, gp1);
    finalizeAff<HID><<<TSUB, 128, 0, stream>>>(gp1, g2, b2, aff2);
    gemm_kernel<1, 1><<<dim3(NMT, TSUB), 512, 0, stream>>>(h1, WT2, aff2, outbuf, gp0);

    finalize3<<<4, 256, 0, stream>>>(gp0, g3, b3, acg);
    scan_kernel<<<NBLK_SCAN, 256, 0, stream>>>(dw, outbuf, acg, z_init, y_init, yout, mred);
    meanred<<<NSTEP, 256, 0, stream>>>(mred, y_init, meanout);
}

// Round 16
// 171.535 us; speedup vs baseline: 1.0436x; 1.0161x over previous
//
#include <hip/hip_runtime.h>

typedef unsigned short u16;
typedef unsigned int   u32;

#define BATCH  8192
#define DIM    100      // D
#define HID    110      // H
#define TSUB   19       // T = N-1 subnets
#define NSTEP  20       // N scan steps
#define KP     128      // padded K for MFMA
#define NPAD   112      // padded N (output cols) for tiles/storage
#define BN_EPS 1e-6f
#define DT_C   0.05f

#define SAB  1024                 // statsA blocks
#define SAR  8                    // rows per block (2 asm batches of 4)
#define SLICES 32                 // statsB slices (1024/32 = 32 rows per slice)
#define NBLK_SCAN 2048
#define NMT  64                   // gemm m-tiles

typedef __bf16 v8bf __attribute__((ext_vector_type(8)));
typedef float  v4f  __attribute__((ext_vector_type(4)));
typedef float  v2f  __attribute__((ext_vector_type(2)));
typedef u16    u16x4 __attribute__((ext_vector_type(4)));

__device__ __forceinline__ u16 f2bf(float f) {
    u32 u = __float_as_uint(f);
    return (u16)((u + 0x7fffu + ((u >> 16) & 1u)) >> 16);   // RNE
}
__device__ __forceinline__ float bf2f(u16 h) {
    return __uint_as_float(((u32)h) << 16);
}

// ---------------------------------------------------------------------------
// statsA v3: inline-asm batched loads (compiler provably sinks HIP-level
// load batches — R14's restructure compiled to VGPR=32 with serialized
// round trips; asm cannot be sunk). Thread tid owns columns 8t..8t+7 via two
// dwordx4 off ONE address (offset 0/16); threads 0..12 own the 52-col tail.
// Two 4-row batches (12 loads in flight each), one vmcnt(0) per batch.
// Outputs: part[SAB][4200] column partials + xT[t][b][d] bf16 transpose.
// ---------------------------------------------------------------------------
__global__ __launch_bounds__(256, 4)
void statsA(const float* __restrict__ x, float* __restrict__ part,
            u32* __restrict__ xT32) {
    __shared__ u16 xls[SAR][2112];     // 33.8 KB
    const int tid = threadIdx.x;
    const int b0 = blockIdx.x * SAR;
    const int tt = (tid < 13) ? tid : 12;

    float s[8], q[8];
#pragma unroll
    for (int j = 0; j < 8; j++) { s[j] = 0.f; q[j] = 0.f; }
    float4 s2 = {0,0,0,0}, q2 = {0,0,0,0};

#pragma unroll
    for (int g = 0; g < 2; g++) {
        v4f va[4], vb[4], vc[4];
#pragma unroll
        for (int r = 0; r < 4; r++) {
            const float* base  = x + (size_t)(b0 + g * 4 + r) * 2100;
            const float* amain = base + 8 * tid;
            const float* atail = base + 2048 + 4 * tt;
            asm volatile("global_load_dwordx4 %0, %1, off"           : "=v"(va[r]) : "v"(amain));
            asm volatile("global_load_dwordx4 %0, %1, off offset:16" : "=v"(vb[r]) : "v"(amain));
            asm volatile("global_load_dwordx4 %0, %1, off"           : "=v"(vc[r]) : "v"(atail));
        }
        asm volatile("s_waitcnt vmcnt(0)" ::: "memory");
        __builtin_amdgcn_sched_barrier(0);
#pragma unroll
        for (int r = 0; r < 4; r++) {
            const int rr = g * 4 + r;
#pragma unroll
            for (int j = 0; j < 4; j++) {
                float a = va[r][j], b = vb[r][j];
                s[j]     += a; q[j]     += a * a;
                s[4 + j] += b; q[4 + j] += b * b;
            }
            u16 pk[8];
#pragma unroll
            for (int j = 0; j < 4; j++) { pk[j] = f2bf(va[r][j]); pk[4 + j] = f2bf(vb[r][j]); }
            *(uint4*)&xls[rr][tid * 8] = *(uint4*)pk;
            if (tid < 13) {
                float4 c = { vc[r][0], vc[r][1], vc[r][2], vc[r][3] };
                s2.x += c.x; s2.y += c.y; s2.z += c.z; s2.w += c.w;
                q2.x += c.x * c.x; q2.y += c.y * c.y; q2.z += c.z * c.z; q2.w += c.w * c.w;
                u16x4 p2 = { f2bf(c.x), f2bf(c.y), f2bf(c.z), f2bf(c.w) };
                *(u16x4*)&xls[rr][2048 + tid * 4] = p2;
            }
        }
    }

    float* ps = part + (size_t)blockIdx.x * 4200;
    *(float4*)&ps[8 * tid]            = *(float4*)&s[0];
    *(float4*)&ps[8 * tid + 4]        = *(float4*)&s[4];
    *(float4*)&ps[2100 + 8 * tid]     = *(float4*)&q[0];
    *(float4*)&ps[2100 + 8 * tid + 4] = *(float4*)&q[4];
    if (tid < 13) {
        *(float4*)&ps[2048 + 4 * tid] = s2;
        *(float4*)&ps[4148 + 4 * tid] = q2;
    }
    __syncthreads();
    const int TOT = TSUB * SAR * (NPAD / 2);   // 19*8*56
    for (int i = tid; i < TOT; i += 256) {
        int w = i % (NPAD / 2);
        int seg = i / (NPAD / 2);
        int r = seg % SAR, t = seg / SAR;
        int d0 = w * 2;
        u32 v = 0;
        if (d0 < DIM) {
            u16 lo = xls[r][d0 * 21 + t + 1];
            u16 hi = (d0 + 1 < DIM) ? xls[r][(d0 + 1) * 21 + t + 1] : (u16)0;
            v = (u32)lo | ((u32)hi << 16);
        }
        xT32[((size_t)t * BATCH + b0 + r) * (NPAD / 2) + w] = v;
    }
}

// statsB: slice partials -> slpart[slice][4200], plain stores
__global__ void statsB(const float* __restrict__ part, float* __restrict__ slpart) {
    int gid = blockIdx.x * 256 + threadIdx.x;
    if (gid >= 4200 * SLICES) return;
    int slice = gid / 4200;
    int o = gid - slice * 4200;
    const float* p = part + (size_t)slice * (SAB / SLICES) * 4200 + o;
    float acc = 0.f;
#pragma unroll 8
    for (int i = 0; i < SAB / SLICES; i++) acc += p[(size_t)i * 4200];
    slpart[(size_t)slice * 4200 + o] = acc;
}

// ---------------------------------------------------------------------------
// wtrans: W[l][t][k][n] f32 -> WTsw[l][t][n][chunk-swizzled k] bf16.
// ---------------------------------------------------------------------------
__global__ void wtrans(const float* __restrict__ W0, const float* __restrict__ W1,
                       const float* __restrict__ W2, u16* __restrict__ WTsw) {
    __shared__ float lw[HID * HID];
    const int t = blockIdx.x, l = blockIdx.y, tid = threadIdx.x;
    const float* W; int K, N;
    if (l == 0)      { W = W0; K = DIM; N = HID; }
    else if (l == 1) { W = W1; K = HID; N = HID; }
    else             { W = W2; K = HID; N = DIM; }
    const float* Wt = W + (size_t)t * K * N;
    for (int i = tid; i < K * N; i += 256) lw[i] = Wt[i];
    __syncthreads();
    u16* out = WTsw + ((size_t)l * TSUB + t) * (NPAD * KP);
    for (int i = tid; i < NPAD * 16; i += 256) {
        int n = i / 16, p = i % 16;
        int kc = p ^ (n & 7);
        u16 o8[8];
#pragma unroll
        for (int j = 0; j < 8; j++) {
            int k = kc * 8 + j;
            float v = (k < K && n < N) ? lw[k * N + n] : 0.f;
            o8[j] = f2bf(v);
        }
        *(uint4*)&out[(size_t)n * KP + p * 8] = *(uint4*)o8;
    }
}

// ---------------------------------------------------------------------------
// finalize0: layer-0 scale table aff0[T][2][KP] from statsB slices.
// a = gamma0*rstd, c = 0 (beta0 cancelled by next BN's shift invariance).
// ---------------------------------------------------------------------------
__global__ void finalize0(const float* __restrict__ slpart, const float* __restrict__ g0,
                          float* __restrict__ aff0) {
    const int t = blockIdx.x, tid = threadIdx.x;   // 128 threads
    float a = 0.f;
    if (tid < DIM) {
        int idx = tid * 21 + (t + 1);
        float s = 0.f, q = 0.f;
#pragma unroll 8
        for (int s2 = 0; s2 < SLICES; s2++) {
            s += slpart[(size_t)s2 * 4200 + idx];
            q += slpart[(size_t)s2 * 4200 + 2100 + idx];
        }
        float m = s * (1.f / BATCH);
        float v = q * (1.f / BATCH) - m * m;
        a = g0[t * DIM + tid] * rsqrtf(v + BN_EPS);
    }
    aff0[(size_t)t * 2 * KP + tid]      = a;
    aff0[(size_t)t * 2 * KP + KP + tid] = 0.f;
}

// ---------------------------------------------------------------------------
// finalizeAff: reduce gpart [NMT][T][2][NPAD] -> aff[T][2][KP] (a, c).
// COALESCED partial reads; k >= KREAL zeroed.
// ---------------------------------------------------------------------------
template <int KREAL>
__global__ void finalizeAff(const float* __restrict__ partIn,
                            const float* __restrict__ g, const float* __restrict__ b,
                            float* __restrict__ aff) {
    const int t = blockIdx.x, tid = threadIdx.x;   // 128 threads
    float a = 0.f, c = 0.f;
    if (tid < KREAL) {
        float s = 0.f, q = 0.f;
#pragma unroll 8
        for (int m2 = 0; m2 < NMT; m2++) {
            const float* pp = partIn + ((size_t)(m2 * TSUB + t) * 2) * NPAD;
            s += pp[tid];
            q += pp[NPAD + tid];
        }
        float m = s * (1.f / BATCH);
        float v = q * (1.f / BATCH) - m * m;
        float rstd = rsqrtf(v + BN_EPS);
        float ga = g[t * KREAL + tid] * rstd;
        a = ga;
        c = b[t * KREAL + tid] - m * ga;
    }
    aff[(size_t)t * 2 * KP + tid]      = a;
    aff[(size_t)t * 2 * KP + KP + tid] = c;
}

// ---------------------------------------------------------------------------
// GEMM v6: A direct global->registers; BN affine read COALESCED from the
// precomputed aff[T][2][KP] table. Column stats out via per-mt plain stores.
// ---------------------------------------------------------------------------
template <int RELU, int BMAJOR>
__global__ __launch_bounds__(512, 4)
void gemm_kernel(const u16* __restrict__ Ain,
                 const u16* __restrict__ WTswL,
                 const float* __restrict__ aff,      // [T][2][KP]
                 u16* __restrict__ Hout,
                 float* __restrict__ partOut) {      // [64][T][2][NPAD]
    __shared__ __align__(16) u16 Blds[NPAD * KP];  // 28 KB
    __shared__ float s_sum[NPAD], s_sq[NPAD];
    __shared__ float aAffL[KP], cAffL[KP];

    const int tid = threadIdx.x;
    const int mt = blockIdx.x;
    const int t  = blockIdx.y;
    const int brow0 = mt * 128;

    if (tid < NPAD) { s_sum[tid] = 0.f; s_sq[tid] = 0.f; }
    if (tid < KP) {
        aAffL[tid] = aff[(size_t)t * 2 * KP + tid];
        cAffL[tid] = aff[(size_t)t * 2 * KP + KP + tid];
    }

    {
        const uint4* wsrc = (const uint4*)(WTswL + (size_t)t * NPAD * KP);
        uint4* bl = (uint4*)Blds;
        for (int i = tid; i < NPAD * KP / 8; i += 512) bl[i] = wsrc[i];
    }
    __syncthreads();

    const int lane = tid & 63;
    const int wv   = tid >> 6;            // 0..7
    const int r0   = lane & 15;
    const int q    = lane >> 4;
    const int row  = wv * 16 + r0;        // 0..127

    const u16* arow = Ain + ((size_t)t * BATCH + brow0 + row) * NPAD;
    u16 hv[4][8];
#pragma unroll
    for (int ks = 0; ks < 4; ks++) {
        int cb = ks * 4 + q;
        int cbl = (cb > 13) ? 13 : cb;    // clamp: k>=112 rows of B are zero
        *(uint4*)hv[ks] = *(const uint4*)(arow + cbl * 8);
    }
    v8bf afr[4];
#pragma unroll
    for (int ks = 0; ks < 4; ks++) {
        int cb = ks * 4 + q;              // k >= KREAL has a=c=0 -> frag 0
        const float* ap = &aAffL[cb * 8];
        const float* cp = &cAffL[cb * 8];
        u16 pk[8];
#pragma unroll
        for (int j = 0; j < 8; j++) {
            float av = fmaf(bf2f(hv[ks][j]), ap[j], cp[j]);
            if (RELU) av = fmaxf(av, 0.f);
            pk[j] = f2bf(av);
        }
        afr[ks] = *(v8bf*)pk;
    }

    v4f acc[7];
#pragma unroll
    for (int j = 0; j < 7; j++) { v4f z = {0.f, 0.f, 0.f, 0.f}; acc[j] = z; }
#pragma unroll
    for (int ks = 0; ks < 4; ks++) {
        int cbase = ks * 4 + q;
#pragma unroll
        for (int nf = 0; nf < 7; nf++) {
            int nr = nf * 16 + r0;
            v8bf bfr = *(const v8bf*)&Blds[nr * KP + ((cbase ^ (nr & 7)) * 8)];
            acc[nf] = __builtin_amdgcn_mfma_f32_16x16x32_bf16(afr[ks], bfr, acc[nf], 0, 0, 0);
        }
    }

#pragma unroll
    for (int nf = 0; nf < 7; nf++) {
        int n = nf * 16 + r0;
#pragma unroll
        for (int rg = 0; rg < 4; rg++) {
            int grow = brow0 + wv * 16 + q * 4 + rg;
            size_t oidx = BMAJOR ? ((size_t)grow * (TSUB * NPAD) + (size_t)t * NPAD + n)
                                 : (((size_t)t * BATCH + grow) * NPAD + n);
            Hout[oidx] = f2bf(acc[nf][rg]);
        }
    }
#pragma unroll
    for (int nf = 0; nf < 7; nf++) {
        float cs = 0.f, cq = 0.f;
#pragma unroll
        for (int rg = 0; rg < 4; rg++) {
            float vv = acc[nf][rg];
            cs += vv; cq += vv * vv;
        }
        cs += __shfl_xor(cs, 16); cs += __shfl_xor(cs, 32);
        cq += __shfl_xor(cq, 16); cq += __shfl_xor(cq, 32);
        if (q == 0) {
            atomicAdd(&s_sum[nf * 16 + r0], cs);   // LDS-only combine across waves
            atomicAdd(&s_sq[nf * 16 + r0], cq);
        }
    }
    __syncthreads();
    if (tid < NPAD) {
        float* pp = partOut + ((size_t)(mt * TSUB + t) * 2) * NPAD;
        pp[tid]        = s_sum[tid];
        pp[NPAD + tid] = s_sq[tid];
    }
}

// ---------------------------------------------------------------------------
// finalize3: BN affine for layer 3 from gemm2's gpart partials, packed per
// d-PAIR as {a0,c0,a1,c1} f32x4, 1/DIM folded.
// ---------------------------------------------------------------------------
__global__ void finalize3(const float* __restrict__ partIn,   // [64][T][2][NPAD]
                          const float* __restrict__ g3, const float* __restrict__ b3,
                          float4* __restrict__ acg) {
    int i = blockIdx.x * 256 + threadIdx.x;      // over 19*50 d-pairs
    if (i >= TSUB * 50) return;
    int t = i / 50, p = i - t * 50;
    float4 o;
#pragma unroll
    for (int h = 0; h < 2; h++) {
        int d = 2 * p + h;
        float s = 0.f, q = 0.f;
#pragma unroll 8
        for (int m2 = 0; m2 < NMT; m2++) {
            const float* pp = partIn + ((size_t)(m2 * TSUB + t) * 2) * NPAD;
            s += pp[d];
            q += pp[NPAD + d];
        }
        float m = s * (1.f / BATCH);
        float v = q * (1.f / BATCH) - m * m;
        float rstd = rsqrtf(v + BN_EPS);
        int e = t * DIM + d;
        float ga = g3[e] * rstd * (1.f / DIM);
        float cc = b3[e] * (1.f / DIM) - m * ga;
        if (h == 0) { o.x = ga; o.y = cc; } else { o.z = ga; o.w = cc; }
    }
    acg[i] = o;
}

// ---------------------------------------------------------------------------
// Scan (R7/R9 structure; launch_bounds(256,4) -> VGPR cap 128, no asm spills).
// ---------------------------------------------------------------------------
__global__ __launch_bounds__(256, 4)
void scan_kernel(const float* __restrict__ dw,
                 const u16* __restrict__ zbuf,          // [B][T][NPAD] (b-major)
                 const float4* __restrict__ acg,        // [19][50] {a0,c0,a1,c1}
                 const float* __restrict__ z_init, const float* __restrict__ y_init,
                 float* __restrict__ yout, float* __restrict__ mred) {
    __shared__ float bsum[NSTEP];
    const int tid = threadIdx.x;
    if (tid < NSTEP) bsum[tid] = 0.f;
    __syncthreads();

    const int wv = tid >> 6, lane = tid & 63;
    const int b = blockIdx.x * 4 + wv;
    const int ll = (lane < 50) ? lane : 49;            // clamp for loads

    v4f w[10];
    u32 zr[TSUB];
    v2f zi;
    {
        const float* dwaddr = dw + (size_t)b * (DIM * NSTEP) + ll * 40;
        const u16*   zaddr  = zbuf + (size_t)b * (TSUB * NPAD) + 2 * ll;
        const float* ziaddr = z_init + 2 * ll;
        asm volatile("global_load_dwordx4 %0, %1, off offset:0"   : "=v"(w[0]) : "v"(dwaddr));
        asm volatile("global_load_dwordx4 %0, %1, off offset:16"  : "=v"(w[1]) : "v"(dwaddr));
        asm volatile("global_load_dwordx4 %0, %1, off offset:32"  : "=v"(w[2]) : "v"(dwaddr));
        asm volatile("global_load_dwordx4 %0, %1, off offset:48"  : "=v"(w[3]) : "v"(dwaddr));
        asm volatile("global_load_dwordx4 %0, %1, off offset:64"  : "=v"(w[4]) : "v"(dwaddr));
        asm volatile("global_load_dwordx4 %0, %1, off offset:80"  : "=v"(w[5]) : "v"(dwaddr));
        asm volatile("global_load_dwordx4 %0, %1, off offset:96"  : "=v"(w[6]) : "v"(dwaddr));
        asm volatile("global_load_dwordx4 %0, %1, off offset:112" : "=v"(w[7]) : "v"(dwaddr));
        asm volatile("global_load_dwordx4 %0, %1, off offset:128" : "=v"(w[8]) : "v"(dwaddr));
        asm volatile("global_load_dwordx4 %0, %1, off offset:144" : "=v"(w[9]) : "v"(dwaddr));
#pragma unroll
        for (int t = 0; t < TSUB; t++)
            asm volatile("global_load_dword %0, %1, off offset:%2"
                         : "=v"(zr[t]) : "v"(zaddr), "i"(t * NPAD * 2));
        asm volatile("global_load_dwordx2 %0, %1, off" : "=v"(zi) : "v"(ziaddr));
        asm volatile("s_waitcnt vmcnt(0)" ::: "memory");
        __builtin_amdgcn_sched_barrier(0);
    }

    float acc[NSTEP];
#pragma unroll
    for (int k = 0; k < NSTEP; k++) acc[k] = 0.f;
    if (lane < 50) {
        acc[0] = zi[0] * w[0][0] + zi[1] * w[5][0];
#pragma unroll
        for (int t = 0; t < TSUB; t++) {
            float4 ac = acg[t * 50 + ll];
            u32 z = zr[t];
            float za0 = fmaf(bf2f((u16)(z & 0xffffu)), ac.x, ac.y);
            float za1 = fmaf(bf2f((u16)(z >> 16)),     ac.z, ac.w);
            const int n = t + 1, j = n >> 2, k = n & 3;   // compile-time per unrolled t
            acc[n] += w[j][k] * za0 + w[5 + j][k] * za1;
        }
    }

#pragma unroll
    for (int m = 1; m < 64; m <<= 1) {
#pragma unroll
        for (int k = 0; k < NSTEP; k++) acc[k] += __shfl_xor(acc[k], m, 64);
    }

    const float yi = y_init[0];
    float y = yi, ysave = 0.f;
#pragma unroll
    for (int i = 0; i < NSTEP; i++) {
        y = y - DT_C * __sinf(y) + acc[i];
        if (i == lane - 1) ysave = y;                  // lane n holds y_n
    }
    if (lane == 0) yout[b] = y;                        // y_final = y_20
    if (lane >= 1 && lane < NSTEP) atomicAdd(&bsum[lane], ysave);
    __syncthreads();
    if (tid >= 1 && tid < NSTEP) mred[blockIdx.x * NSTEP + tid] = bsum[tid];
}

// ---------------------------------------------------------------------------
// meanred: meanout[n] = mean over batch of y_n (block n sums 2048 partials).
// ---------------------------------------------------------------------------
__global__ void meanred(const float* __restrict__ mred, const float* __restrict__ y_init,
                        float* __restrict__ meanout) {
    const int n = blockIdx.x, tid = threadIdx.x;
    if (n == 0) { if (tid == 0) meanout[0] = y_init[0]; return; }
    float s = 0.f;
    for (int i = tid; i < NBLK_SCAN; i += 256) s += mred[(size_t)i * NSTEP + n];
#pragma unroll
    for (int m = 1; m < 64; m <<= 1) s += __shfl_xor(s, m, 64);
    __shared__ float ws4[4];
    if ((tid & 63) == 0) ws4[tid >> 6] = s;
    __syncthreads();
    if (tid == 0) meanout[n] = (ws4[0] + ws4[1] + ws4[2] + ws4[3]) * (1.f / BATCH);
}

// ---------------------------------------------------------------------------
extern "C" void kernel_launch(void* const* d_in, const int* in_sizes, int n_in,
                              void* d_out, int out_size, void* d_ws, size_t ws_size,
                              hipStream_t stream) {
    const float* dw     = (const float*)d_in[0];
    const float* x      = (const float*)d_in[1];
    const float* y_init = (const float*)d_in[3];
    const float* z_init = (const float*)d_in[4];
    const float* g0 = (const float*)d_in[5];
    const float* W0 = (const float*)d_in[7];
    const float* g1 = (const float*)d_in[8];
    const float* b1 = (const float*)d_in[9];
    const float* W1 = (const float*)d_in[10];
    const float* g2 = (const float*)d_in[11];
    const float* b2 = (const float*)d_in[12];
    const float* W2 = (const float*)d_in[13];
    // d_in[6]=beta0 (cancelled via shift-invariance), d_in[14]=bias2 (cancelled)
    const float* g3 = (const float*)d_in[15];
    const float* b3 = (const float*)d_in[16];

    char* ws = (char*)d_ws;
    size_t off = 0;
    auto alloc = [&](size_t bytes) -> void* {
        off = (off + 255) & ~(size_t)255;
        void* p = ws + off;
        off += bytes;
        return p;
    };

    float* slpart = (float*)alloc((size_t)SLICES * 4200 * 4);         // 537 KB
    float* gp0    = (float*)alloc((size_t)NMT * TSUB * 2 * NPAD * 4); // 1.09 MB
    float* gp1    = (float*)alloc((size_t)NMT * TSUB * 2 * NPAD * 4); // 1.09 MB
    float* aff0   = (float*)alloc((size_t)TSUB * 2 * KP * 4);         // 19.5 KB
    float* aff1   = (float*)alloc((size_t)TSUB * 2 * KP * 4);
    float* aff2   = (float*)alloc((size_t)TSUB * 2 * KP * 4);

    u16* WTsw = (u16*)alloc((size_t)3 * TSUB * NPAD * KP * 2);
    float4* acg = (float4*)alloc((size_t)TSUB * 50 * 16);             // 15.2 KB
    float* mred = (float*)alloc((size_t)NBLK_SCAN * NSTEP * 4);       // 160 KB

    const size_t hBytes = (size_t)TSUB * BATCH * NPAD * 2;            // 34.9 MB
    u16* h0 = (u16*)alloc(hBytes);
    u16* h1 = (u16*)alloc(hBytes);
    u16* outbuf = h0;                 // b-major [B][T][NPAD]; h0 dead after gemm1
    float* part = (float*)h0;         // statsA partials alias h0 (17.2 MB <= 34.9)
    u32*  xT32  = (u32*)h1;           // xT aliases h1

    float* yout = (float*)d_out;
    float* meanout = yout + BATCH;

    wtrans<<<dim3(TSUB, 3), 256, 0, stream>>>(W0, W1, W2, WTsw);
    statsA<<<SAB, 256, 0, stream>>>(x, part, xT32);
    statsB<<<(4200 * SLICES + 255) / 256, 256, 0, stream>>>(part, slpart);
    finalize0<<<TSUB, 128, 0, stream>>>(slpart, g0, aff0);

    const u16* xT = (const u16*)xT32;
    u16* WT0 = WTsw;
    u16* WT1 = WTsw + (size_t)TSUB * NPAD * KP;
    u16* WT2 = WTsw + (size_t)2 * TSUB * NPAD * KP;

    gemm_kernel<0, 0><<<dim3(NMT, TSUB), 512, 0, stream>>>(xT, WT0, aff0, h0, gp0);
    finalizeAff<HID><<<TSUB, 128, 0, stream>>>(gp0, g1, b1, aff1);
    gemm_kernel<1, 0><<<dim3(NMT, TSUB), 512, 0, stream>>>(h0, WT1, aff1, h1, gp1);
    finalizeAff<HID><<<TSUB, 128, 0, stream>>>(gp1, g2, b2, aff2);
    gemm_kernel<1, 1><<<dim3(NMT, TSUB), 512, 0, stream>>>(h1, WT2, aff2, outbuf, gp0);

    finalize3<<<4, 256, 0, stream>>>(gp0, g3, b3, acg);
    scan_kernel<<<NBLK_SCAN, 256, 0, stream>>>(dw, outbuf, acg, z_init, y_init, yout, mred);
    meanred<<<NSTEP, 256, 0, stream>>>(mred, y_init, meanout);
}

// Round 18
// 170.576 us; speedup vs baseline: 1.0494x; 1.0056x over previous
//
#include <hip/hip_runtime.h>

typedef unsigned short u16;
typedef unsigned int   u32;

#define BATCH  8192
#define DIM    100      // D
#define HID    110      // H
#define TSUB   19       // T = N-1 subnets
#define NSTEP  20       // N scan steps
#define KP     128      // padded K for MFMA
#define NPAD   112      // padded N (output cols) for tiles/storage
#define BN_EPS 1e-6f
#define DT_C   0.05f

#define SAB  1024                 // statsA blocks
#define SAR  8                    // rows per block (2 asm batches of 4)
#define SLICES 32                 // statsB slices (1024/32 = 32 rows per slice)
#define NBLK_SCAN 2048
#define NMT  64                   // gemm m-tiles

typedef __bf16 v8bf __attribute__((ext_vector_type(8)));
typedef float  v4f  __attribute__((ext_vector_type(4)));
typedef float  v2f  __attribute__((ext_vector_type(2)));
typedef u16    u16x4 __attribute__((ext_vector_type(4)));

__device__ __forceinline__ u16 f2bf(float f) {
    u32 u = __float_as_uint(f);
    return (u16)((u + 0x7fffu + ((u >> 16) & 1u)) >> 16);   // RNE
}
__device__ __forceinline__ float bf2f(u16 h) {
    return __uint_as_float(((u32)h) << 16);
}

// ---------------------------------------------------------------------------
// statsA v5 = v4 structure (halved 16.9 KB LDS, per-batch xT flush) with
// launch_bounds(256,4): VGPR cap 128. R17's (256,6) cap=84 spilled inline-asm
// load outputs -> scratch store raced the in-flight global_load (silent
// corruption; same mechanism as R10). LAW: asm-load kernels need cap >= 128.
// Occupancy: 4 blocks/CU x 4 waves = 50% cap (R16 measured 27.7% at 33.8 KB).
// ---------------------------------------------------------------------------
__global__ __launch_bounds__(256, 4)
void statsA(const float* __restrict__ x, float* __restrict__ part,
            u32* __restrict__ xT32) {
    __shared__ u16 xls[4][2112];       // 16.9 KB
    const int tid = threadIdx.x;
    const int b0 = blockIdx.x * SAR;
    const int tt = (tid < 13) ? tid : 12;

    float s[8], q[8];
#pragma unroll
    for (int j = 0; j < 8; j++) { s[j] = 0.f; q[j] = 0.f; }
    float4 s2 = {0,0,0,0}, q2 = {0,0,0,0};

#pragma unroll
    for (int g = 0; g < 2; g++) {
        v4f va[4], vb[4], vc[4];
#pragma unroll
        for (int r = 0; r < 4; r++) {
            const float* base  = x + (size_t)(b0 + g * 4 + r) * 2100;
            const float* amain = base + 8 * tid;
            const float* atail = base + 2048 + 4 * tt;
            asm volatile("global_load_dwordx4 %0, %1, off"           : "=v"(va[r]) : "v"(amain));
            asm volatile("global_load_dwordx4 %0, %1, off offset:16" : "=v"(vb[r]) : "v"(amain));
            asm volatile("global_load_dwordx4 %0, %1, off"           : "=v"(vc[r]) : "v"(atail));
        }
        asm volatile("s_waitcnt vmcnt(0)" ::: "memory");
        __builtin_amdgcn_sched_barrier(0);
#pragma unroll
        for (int r = 0; r < 4; r++) {
#pragma unroll
            for (int j = 0; j < 4; j++) {
                float a = va[r][j], b = vb[r][j];
                s[j]     += a; q[j]     += a * a;
                s[4 + j] += b; q[4 + j] += b * b;
            }
            u16 pk[8];
#pragma unroll
            for (int j = 0; j < 4; j++) { pk[j] = f2bf(va[r][j]); pk[4 + j] = f2bf(vb[r][j]); }
            *(uint4*)&xls[r][tid * 8] = *(uint4*)pk;
            if (tid < 13) {
                float4 c = { vc[r][0], vc[r][1], vc[r][2], vc[r][3] };
                s2.x += c.x; s2.y += c.y; s2.z += c.z; s2.w += c.w;
                q2.x += c.x * c.x; q2.y += c.y * c.y; q2.z += c.z * c.z; q2.w += c.w * c.w;
                u16x4 p2 = { f2bf(c.x), f2bf(c.y), f2bf(c.z), f2bf(c.w) };
                *(u16x4*)&xls[r][2048 + tid * 4] = p2;
            }
        }
        __syncthreads();
        // flush xT for this 4-row batch
        const int TOT4 = TSUB * 4 * (NPAD / 2);   // 4256
        for (int i = tid; i < TOT4; i += 256) {
            int w = i % (NPAD / 2);
            int seg = i / (NPAD / 2);
            int r = seg & 3, t = seg >> 2;
            int d0 = w * 2;
            u32 v = 0;
            if (d0 < DIM) {
                u16 lo = xls[r][d0 * 21 + t + 1];
                u16 hi = (d0 + 1 < DIM) ? xls[r][(d0 + 1) * 21 + t + 1] : (u16)0;
                v = (u32)lo | ((u32)hi << 16);
            }
            xT32[((size_t)t * BATCH + b0 + g * 4 + r) * (NPAD / 2) + w] = v;
        }
        __syncthreads();   // xls fully consumed before next batch overwrites
    }

    float* ps = part + (size_t)blockIdx.x * 4200;
    *(float4*)&ps[8 * tid]            = *(float4*)&s[0];
    *(float4*)&ps[8 * tid + 4]        = *(float4*)&s[4];
    *(float4*)&ps[2100 + 8 * tid]     = *(float4*)&q[0];
    *(float4*)&ps[2100 + 8 * tid + 4] = *(float4*)&q[4];
    if (tid < 13) {
        *(float4*)&ps[2048 + 4 * tid] = s2;
        *(float4*)&ps[4148 + 4 * tid] = q2;
    }
}

// statsB: slice partials -> slpart[slice][4200], plain stores
__global__ void statsB(const float* __restrict__ part, float* __restrict__ slpart) {
    int gid = blockIdx.x * 256 + threadIdx.x;
    if (gid >= 4200 * SLICES) return;
    int slice = gid / 4200;
    int o = gid - slice * 4200;
    const float* p = part + (size_t)slice * (SAB / SLICES) * 4200 + o;
    float acc = 0.f;
#pragma unroll 8
    for (int i = 0; i < SAB / SLICES; i++) acc += p[(size_t)i * 4200];
    slpart[(size_t)slice * 4200 + o] = acc;
}

// ---------------------------------------------------------------------------
// wtrans: W[l][t][k][n] f32 -> WTsw[l][t][n][chunk-swizzled k] bf16.
// ---------------------------------------------------------------------------
__global__ void wtrans(const float* __restrict__ W0, const float* __restrict__ W1,
                       const float* __restrict__ W2, u16* __restrict__ WTsw) {
    __shared__ float lw[HID * HID];
    const int t = blockIdx.x, l = blockIdx.y, tid = threadIdx.x;
    const float* W; int K, N;
    if (l == 0)      { W = W0; K = DIM; N = HID; }
    else if (l == 1) { W = W1; K = HID; N = HID; }
    else             { W = W2; K = HID; N = DIM; }
    const float* Wt = W + (size_t)t * K * N;
    for (int i = tid; i < K * N; i += 256) lw[i] = Wt[i];
    __syncthreads();
    u16* out = WTsw + ((size_t)l * TSUB + t) * (NPAD * KP);
    for (int i = tid; i < NPAD * 16; i += 256) {
        int n = i / 16, p = i % 16;
        int kc = p ^ (n & 7);
        u16 o8[8];
#pragma unroll
        for (int j = 0; j < 8; j++) {
            int k = kc * 8 + j;
            float v = (k < K && n < N) ? lw[k * N + n] : 0.f;
            o8[j] = f2bf(v);
        }
        *(uint4*)&out[(size_t)n * KP + p * 8] = *(uint4*)o8;
    }
}

// ---------------------------------------------------------------------------
// finalize0: layer-0 scale table aff0[T][2][KP] from statsB slices.
// a = gamma0*rstd, c = 0 (beta0 cancelled by next BN's shift invariance).
// ---------------------------------------------------------------------------
__global__ void finalize0(const float* __restrict__ slpart, const float* __restrict__ g0,
                          float* __restrict__ aff0) {
    const int t = blockIdx.x, tid = threadIdx.x;   // 128 threads
    float a = 0.f;
    if (tid < DIM) {
        int idx = tid * 21 + (t + 1);
        float s = 0.f, q = 0.f;
#pragma unroll 8
        for (int s2 = 0; s2 < SLICES; s2++) {
            s += slpart[(size_t)s2 * 4200 + idx];
            q += slpart[(size_t)s2 * 4200 + 2100 + idx];
        }
        float m = s * (1.f / BATCH);
        float v = q * (1.f / BATCH) - m * m;
        a = g0[t * DIM + tid] * rsqrtf(v + BN_EPS);
    }
    aff0[(size_t)t * 2 * KP + tid]      = a;
    aff0[(size_t)t * 2 * KP + KP + tid] = 0.f;
}

// ---------------------------------------------------------------------------
// finalizeAff: reduce gpart [NMT][T][2][NPAD] -> aff[T][2][KP] (a, c).
// COALESCED partial reads; k >= KREAL zeroed.
// ---------------------------------------------------------------------------
template <int KREAL>
__global__ void finalizeAff(const float* __restrict__ partIn,
                            const float* __restrict__ g, const float* __restrict__ b,
                            float* __restrict__ aff) {
    const int t = blockIdx.x, tid = threadIdx.x;   // 128 threads
    float a = 0.f, c = 0.f;
    if (tid < KREAL) {
        float s = 0.f, q = 0.f;
#pragma unroll 8
        for (int m2 = 0; m2 < NMT; m2++) {
            const float* pp = partIn + ((size_t)(m2 * TSUB + t) * 2) * NPAD;
            s += pp[tid];
            q += pp[NPAD + tid];
        }
        float m = s * (1.f / BATCH);
        float v = q * (1.f / BATCH) - m * m;
        float rstd = rsqrtf(v + BN_EPS);
        float ga = g[t * KREAL + tid] * rstd;
        a = ga;
        c = b[t * KREAL + tid] - m * ga;
    }
    aff[(size_t)t * 2 * KP + tid]      = a;
    aff[(size_t)t * 2 * KP + KP + tid] = c;
}

// ---------------------------------------------------------------------------
// GEMM v6: A direct global->registers; BN affine read COALESCED from the
// precomputed aff[T][2][KP] table. Column stats out via per-mt plain stores.
// ---------------------------------------------------------------------------
template <int RELU, int BMAJOR>
__global__ __launch_bounds__(512, 4)
void gemm_kernel(const u16* __restrict__ Ain,
                 const u16* __restrict__ WTswL,
                 const float* __restrict__ aff,      // [T][2][KP]
                 u16* __restrict__ Hout,
                 float* __restrict__ partOut) {      // [64][T][2][NPAD]
    __shared__ __align__(16) u16 Blds[NPAD * KP];  // 28 KB
    __shared__ float s_sum[NPAD], s_sq[NPAD];
    __shared__ float aAffL[KP], cAffL[KP];

    const int tid = threadIdx.x;
    const int mt = blockIdx.x;
    const int t  = blockIdx.y;
    const int brow0 = mt * 128;

    if (tid < NPAD) { s_sum[tid] = 0.f; s_sq[tid] = 0.f; }
    if (tid < KP) {
        aAffL[tid] = aff[(size_t)t * 2 * KP + tid];
        cAffL[tid] = aff[(size_t)t * 2 * KP + KP + tid];
    }

    {
        const uint4* wsrc = (const uint4*)(WTswL + (size_t)t * NPAD * KP);
        uint4* bl = (uint4*)Blds;
        for (int i = tid; i < NPAD * KP / 8; i += 512) bl[i] = wsrc[i];
    }
    __syncthreads();

    const int lane = tid & 63;
    const int wv   = tid >> 6;            // 0..7
    const int r0   = lane & 15;
    const int q    = lane >> 4;
    const int row  = wv * 16 + r0;        // 0..127

    const u16* arow = Ain + ((size_t)t * BATCH + brow0 + row) * NPAD;
    u16 hv[4][8];
#pragma unroll
    for (int ks = 0; ks < 4; ks++) {
        int cb = ks * 4 + q;
        int cbl = (cb > 13) ? 13 : cb;    // clamp: k>=112 rows of B are zero
        *(uint4*)hv[ks] = *(const uint4*)(arow + cbl * 8);
    }
    v8bf afr[4];
#pragma unroll
    for (int ks = 0; ks < 4; ks++) {
        int cb = ks * 4 + q;              // k >= KREAL has a=c=0 -> frag 0
        const float* ap = &aAffL[cb * 8];
        const float* cp = &cAffL[cb * 8];
        u16 pk[8];
#pragma unroll
        for (int j = 0; j < 8; j++) {
            float av = fmaf(bf2f(hv[ks][j]), ap[j], cp[j]);
            if (RELU) av = fmaxf(av, 0.f);
            pk[j] = f2bf(av);
        }
        afr[ks] = *(v8bf*)pk;
    }

    v4f acc[7];
#pragma unroll
    for (int j = 0; j < 7; j++) { v4f z = {0.f, 0.f, 0.f, 0.f}; acc[j] = z; }
#pragma unroll
    for (int ks = 0; ks < 4; ks++) {
        int cbase = ks * 4 + q;
#pragma unroll
        for (int nf = 0; nf < 7; nf++) {
            int nr = nf * 16 + r0;
            v8bf bfr = *(const v8bf*)&Blds[nr * KP + ((cbase ^ (nr & 7)) * 8)];
            acc[nf] = __builtin_amdgcn_mfma_f32_16x16x32_bf16(afr[ks], bfr, acc[nf], 0, 0, 0);
        }
    }

#pragma unroll
    for (int nf = 0; nf < 7; nf++) {
        int n = nf * 16 + r0;
#pragma unroll
        for (int rg = 0; rg < 4; rg++) {
            int grow = brow0 + wv * 16 + q * 4 + rg;
            size_t oidx = BMAJOR ? ((size_t)grow * (TSUB * NPAD) + (size_t)t * NPAD + n)
                                 : (((size_t)t * BATCH + grow) * NPAD + n);
            Hout[oidx] = f2bf(acc[nf][rg]);
        }
    }
#pragma unroll
    for (int nf = 0; nf < 7; nf++) {
        float cs = 0.f, cq = 0.f;
#pragma unroll
        for (int rg = 0; rg < 4; rg++) {
            float vv = acc[nf][rg];
            cs += vv; cq += vv * vv;
        }
        cs += __shfl_xor(cs, 16); cs += __shfl_xor(cs, 32);
        cq += __shfl_xor(cq, 16); cq += __shfl_xor(cq, 32);
        if (q == 0) {
            atomicAdd(&s_sum[nf * 16 + r0], cs);   // LDS-only combine across waves
            atomicAdd(&s_sq[nf * 16 + r0], cq);
        }
    }
    __syncthreads();
    if (tid < NPAD) {
        float* pp = partOut + ((size_t)(mt * TSUB + t) * 2) * NPAD;
        pp[tid]        = s_sum[tid];
        pp[NPAD + tid] = s_sq[tid];
    }
}

// ---------------------------------------------------------------------------
// finalize3: BN affine for layer 3 from gemm2's gpart partials, packed per
// d-PAIR as {a0,c0,a1,c1} f32x4, 1/DIM folded.
// ---------------------------------------------------------------------------
__global__ void finalize3(const float* __restrict__ partIn,   // [64][T][2][NPAD]
                          const float* __restrict__ g3, const float* __restrict__ b3,
                          float4* __restrict__ acg) {
    int i = blockIdx.x * 256 + threadIdx.x;      // over 19*50 d-pairs
    if (i >= TSUB * 50) return;
    int t = i / 50, p = i - t * 50;
    float4 o;
#pragma unroll
    for (int h = 0; h < 2; h++) {
        int d = 2 * p + h;
        float s = 0.f, q = 0.f;
#pragma unroll 8
        for (int m2 = 0; m2 < NMT; m2++) {
            const float* pp = partIn + ((size_t)(m2 * TSUB + t) * 2) * NPAD;
            s += pp[d];
            q += pp[NPAD + d];
        }
        float m = s * (1.f / BATCH);
        float v = q * (1.f / BATCH) - m * m;
        float rstd = rsqrtf(v + BN_EPS);
        int e = t * DIM + d;
        float ga = g3[e] * rstd * (1.f / DIM);
        float cc = b3[e] * (1.f / DIM) - m * ga;
        if (h == 0) { o.x = ga; o.y = cc; } else { o.z = ga; o.w = cc; }
    }
    acg[i] = o;
}

// ---------------------------------------------------------------------------
// Scan (R7/R9 structure; launch_bounds(256,4) -> VGPR cap 128, no asm spills).
// ---------------------------------------------------------------------------
__global__ __launch_bounds__(256, 4)
void scan_kernel(const float* __restrict__ dw,
                 const u16* __restrict__ zbuf,          // [B][T][NPAD] (b-major)
                 const float4* __restrict__ acg,        // [19][50] {a0,c0,a1,c1}
                 const float* __restrict__ z_init, const float* __restrict__ y_init,
                 float* __restrict__ yout, float* __restrict__ mred) {
    __shared__ float bsum[NSTEP];
    const int tid = threadIdx.x;
    if (tid < NSTEP) bsum[tid] = 0.f;
    __syncthreads();

    const int wv = tid >> 6, lane = tid & 63;
    const int b = blockIdx.x * 4 + wv;
    const int ll = (lane < 50) ? lane : 49;            // clamp for loads

    v4f w[10];
    u32 zr[TSUB];
    v2f zi;
    {
        const float* dwaddr = dw + (size_t)b * (DIM * NSTEP) + ll * 40;
        const u16*   zaddr  = zbuf + (size_t)b * (TSUB * NPAD) + 2 * ll;
        const float* ziaddr = z_init + 2 * ll;
        asm volatile("global_load_dwordx4 %0, %1, off offset:0"   : "=v"(w[0]) : "v"(dwaddr));
        asm volatile("global_load_dwordx4 %0, %1, off offset:16"  : "=v"(w[1]) : "v"(dwaddr));
        asm volatile("global_load_dwordx4 %0, %1, off offset:32"  : "=v"(w[2]) : "v"(dwaddr));
        asm volatile("global_load_dwordx4 %0, %1, off offset:48"  : "=v"(w[3]) : "v"(dwaddr));
        asm volatile("global_load_dwordx4 %0, %1, off offset:64"  : "=v"(w[4]) : "v"(dwaddr));
        asm volatile("global_load_dwordx4 %0, %1, off offset:80"  : "=v"(w[5]) : "v"(dwaddr));
        asm volatile("global_load_dwordx4 %0, %1, off offset:96"  : "=v"(w[6]) : "v"(dwaddr));
        asm volatile("global_load_dwordx4 %0, %1, off offset:112" : "=v"(w[7]) : "v"(dwaddr));
        asm volatile("global_load_dwordx4 %0, %1, off offset:128" : "=v"(w[8]) : "v"(dwaddr));
        asm volatile("global_load_dwordx4 %0, %1, off offset:144" : "=v"(w[9]) : "v"(dwaddr));
#pragma unroll
        for (int t = 0; t < TSUB; t++)
            asm volatile("global_load_dword %0, %1, off offset:%2"
                         : "=v"(zr[t]) : "v"(zaddr), "i"(t * NPAD * 2));
        asm volatile("global_load_dwordx2 %0, %1, off" : "=v"(zi) : "v"(ziaddr));
        asm volatile("s_waitcnt vmcnt(0)" ::: "memory");
        __builtin_amdgcn_sched_barrier(0);
    }

    float acc[NSTEP];
#pragma unroll
    for (int k = 0; k < NSTEP; k++) acc[k] = 0.f;
    if (lane < 50) {
        acc[0] = zi[0] * w[0][0] + zi[1] * w[5][0];
#pragma unroll
        for (int t = 0; t < TSUB; t++) {
            float4 ac = acg[t * 50 + ll];
            u32 z = zr[t];
            float za0 = fmaf(bf2f((u16)(z & 0xffffu)), ac.x, ac.y);
            float za1 = fmaf(bf2f((u16)(z >> 16)),     ac.z, ac.w);
            const int n = t + 1, j = n >> 2, k = n & 3;   // compile-time per unrolled t
            acc[n] += w[j][k] * za0 + w[5 + j][k] * za1;
        }
    }

#pragma unroll
    for (int m = 1; m < 64; m <<= 1) {
#pragma unroll
        for (int k = 0; k < NSTEP; k++) acc[k] += __shfl_xor(acc[k], m, 64);
    }

    const float yi = y_init[0];
    float y = yi, ysave = 0.f;
#pragma unroll
    for (int i = 0; i < NSTEP; i++) {
        y = y - DT_C * __sinf(y) + acc[i];
        if (i == lane - 1) ysave = y;                  // lane n holds y_n
    }
    if (lane == 0) yout[b] = y;                        // y_final = y_20
    if (lane >= 1 && lane < NSTEP) atomicAdd(&bsum[lane], ysave);
    __syncthreads();
    if (tid >= 1 && tid < NSTEP) mred[blockIdx.x * NSTEP + tid] = bsum[tid];
}

// ---------------------------------------------------------------------------
// meanred: meanout[n] = mean over batch of y_n (block n sums 2048 partials).
// ---------------------------------------------------------------------------
__global__ void meanred(const float* __restrict__ mred, const float* __restrict__ y_init,
                        float* __restrict__ meanout) {
    const int n = blockIdx.x, tid = threadIdx.x;
    if (n == 0) { if (tid == 0) meanout[0] = y_init[0]; return; }
    float s = 0.f;
    for (int i = tid; i < NBLK_SCAN; i += 256) s += mred[(size_t)i * NSTEP + n];
#pragma unroll
    for (int m = 1; m < 64; m <<= 1) s += __shfl_xor(s, m, 64);
    __shared__ float ws4[4];
    if ((tid & 63) == 0) ws4[tid >> 6] = s;
    __syncthreads();
    if (tid == 0) meanout[n] = (ws4[0] + ws4[1] + ws4[2] + ws4[3]) * (1.f / BATCH);
}

// ---------------------------------------------------------------------------
extern "C" void kernel_launch(void* const* d_in, const int* in_sizes, int n_in,
                              void* d_out, int out_size, void* d_ws, size_t ws_size,
                              hipStream_t stream) {
    const float* dw     = (const float*)d_in[0];
    const float* x      = (const float*)d_in[1];
    const float* y_init = (const float*)d_in[3];
    const float* z_init = (const float*)d_in[4];
    const float* g0 = (const float*)d_in[5];
    const float* W0 = (const float*)d_in[7];
    const float* g1 = (const float*)d_in[8];
    const float* b1 = (const float*)d_in[9];
    const float* W1 = (const float*)d_in[10];
    const float* g2 = (const float*)d_in[11];
    const float* b2 = (const float*)d_in[12];
    const float* W2 = (const float*)d_in[13];
    // d_in[6]=beta0 (cancelled via shift-invariance), d_in[14]=bias2 (cancelled)
    const float* g3 = (const float*)d_in[15];
    const float* b3 = (const float*)d_in[16];

    char* ws = (char*)d_ws;
    size_t off = 0;
    auto alloc = [&](size_t bytes) -> void* {
        off = (off + 255) & ~(size_t)255;
        void* p = ws + off;
        off += bytes;
        return p;
    };

    float* slpart = (float*)alloc((size_t)SLICES * 4200 * 4);         // 537 KB
    float* gp0    = (float*)alloc((size_t)NMT * TSUB * 2 * NPAD * 4); // 1.09 MB
    float* gp1    = (float*)alloc((size_t)NMT * TSUB * 2 * NPAD * 4); // 1.09 MB
    float* aff0   = (float*)alloc((size_t)TSUB * 2 * KP * 4);         // 19.5 KB
    float* aff1   = (float*)alloc((size_t)TSUB * 2 * KP * 4);
    float* aff2   = (float*)alloc((size_t)TSUB * 2 * KP * 4);

    u16* WTsw = (u16*)alloc((size_t)3 * TSUB * NPAD * KP * 2);
    float4* acg = (float4*)alloc((size_t)TSUB * 50 * 16);             // 15.2 KB
    float* mred = (float*)alloc((size_t)NBLK_SCAN * NSTEP * 4);       // 160 KB

    const size_t hBytes = (size_t)TSUB * BATCH * NPAD * 2;            // 34.9 MB
    u16* h0 = (u16*)alloc(hBytes);
    u16* h1 = (u16*)alloc(hBytes);
    u16* outbuf = h0;                 // b-major [B][T][NPAD]; h0 dead after gemm1
    float* part = (float*)h0;         // statsA partials alias h0 (17.2 MB <= 34.9)
    u32*  xT32  = (u32*)h1;           // xT aliases h1

    float* yout = (float*)d_out;
    float* meanout = yout + BATCH;

    wtrans<<<dim3(TSUB, 3), 256, 0, stream>>>(W0, W1, W2, WTsw);
    statsA<<<SAB, 256, 0, stream>>>(x, part, xT32);
    statsB<<<(4200 * SLICES + 255) / 256, 256, 0, stream>>>(part, slpart);
    finalize0<<<TSUB, 128, 0, stream>>>(slpart, g0, aff0);

    const u16* xT = (const u16*)xT32;
    u16* WT0 = WTsw;
    u16* WT1 = WTsw + (size_t)TSUB * NPAD * KP;
    u16* WT2 = WTsw + (size_t)2 * TSUB * NPAD * KP;

    gemm_kernel<0, 0><<<dim3(NMT, TSUB), 512, 0, stream>>>(xT, WT0, aff0, h0, gp0);
    finalizeAff<HID><<<TSUB, 128, 0, stream>>>(gp0, g1, b1, aff1);
    gemm_kernel<1, 0><<<dim3(NMT, TSUB), 512, 0, stream>>>(h0, WT1, aff1, h1, gp1);
    finalizeAff<HID><<<TSUB, 128, 0, stream>>>(gp1, g2, b2, aff2);
    gemm_kernel<1, 1><<<dim3(NMT, TSUB), 512, 0, stream>>>(h1, WT2, aff2, outbuf, gp0);

    finalize3<<<4, 256, 0, stream>>>(gp0, g3, b3, acg);
    scan_kernel<<<NBLK_SCAN, 256, 0, stream>>>(dw, outbuf, acg, z_init, y_init, yout, mred);
    meanred<<<NSTEP, 256, 0, stream>>>(mred, y_init, meanout);
}